// Round 8
// baseline (195.951 us; speedup 1.0000x reference)
//
#include <hip/hip_runtime.h>

#define T_SEQ   2048
#define NHEADS  12
#define DHEAD   64
#define WIN     16
#define WW      32
#define NWIN    128
#define DMODEL  768
#define NABCDE  3840
#define IGNORE_V (-1.0e6f)
#define PAD_K   72          // bf16 LDS row stride (144 B, 16B-aligned)
#define L2E64   0.022542110013890053f   // log2(e)/64

typedef float f32x4 __attribute__((ext_vector_type(4)));
typedef float f32x2 __attribute__((ext_vector_type(2)));
typedef short bf16x8 __attribute__((ext_vector_type(8)));

__device__ __forceinline__ short f2bf(float f) {
    unsigned u = __float_as_uint(f);
    unsigned r = (u + 0x7FFF + ((u >> 16) & 1)) >> 16;   // RNE
    return (short)r;
}

__device__ __forceinline__ void gload_lds16(const short* g, short* l) {
    __builtin_amdgcn_global_load_lds(
        (const __attribute__((address_space(1))) void*)g,
        (__attribute__((address_space(3))) void*)l,
        16, 0, 0);
}

// ---------------------------------------------------------------------------
// merged prep: [0,1536) cast x -> xb; [1536,4416) transpose W_abcde -> Wt;
// [4416,4992) transpose W_O -> WOt.
// ---------------------------------------------------------------------------
__global__ __launch_bounds__(256) void prep_kernel(
    const float* __restrict__ x, const float* __restrict__ W_abcde,
    const float* __restrict__ W_O,
    short* __restrict__ xb, short* __restrict__ Wt, short* __restrict__ WOt)
{
    __shared__ float tile[32][33];
    const int blk = blockIdx.x;
    const int tid = threadIdx.x;

    if (blk < 1536) {
        int i = (blk * 256 + tid) * 8;
        float4 a = *reinterpret_cast<const float4*>(&x[i]);
        float4 b = *reinterpret_cast<const float4*>(&x[i + 4]);
        union { short s[8]; uint4 u; } r;
        r.s[0] = f2bf(a.x); r.s[1] = f2bf(a.y); r.s[2] = f2bf(a.z); r.s[3] = f2bf(a.w);
        r.s[4] = f2bf(b.x); r.s[5] = f2bf(b.y); r.s[6] = f2bf(b.z); r.s[7] = f2bf(b.w);
        *reinterpret_cast<uint4*>(&xb[i]) = r.u;
        return;
    }
    const float* W; short* Wo; int N, bx, by;
    if (blk < 4416) {
        int t = blk - 1536;
        W = W_abcde; Wo = Wt; N = NABCDE;
        bx = (t % 120) * 32; by = (t / 120) * 32;
    } else {
        int t = blk - 4416;
        W = W_O; Wo = WOt; N = DMODEL;
        bx = (t % 24) * 32; by = (t / 24) * 32;
    }
    const int tx = tid & 31, ty = tid >> 5;
#pragma unroll
    for (int r = 0; r < 32; r += 8)
        tile[ty + r][tx] = W[(size_t)(by + ty + r) * N + bx + tx];
    __syncthreads();
#pragma unroll
    for (int r = 0; r < 32; r += 8)
        Wo[(size_t)(bx + ty + r) * DMODEL + by + tx] = f2bf(tile[tx][ty + r]);
}

// ---------------------------------------------------------------------------
// bf16 MFMA GEMM, 128x64 tile, BK=64 dual 32-wide LDS buffers, balanced
// staging (24 glds chunks, 6 per wave). BF16OUT selects output type.
// ---------------------------------------------------------------------------
template <bool BF16OUT>
__global__ __launch_bounds__(256) void gemm_bf16_n64(
    const short* __restrict__ A, const short* __restrict__ Bt,
    const float* __restrict__ bias, void* __restrict__ Cv,
    int M, int N, int K)
{
    __shared__ short As[2][128 * 32];
    __shared__ short Bs[2][64 * 32];

    const int tid  = threadIdx.x;
    const int wave = tid >> 6;
    const int lane = tid & 63;
    const int bm = blockIdx.y * 128;
    const int bn = blockIdx.x * 64;

    const int st_row = lane >> 2;
    const int st_col = (lane & 3) * 8;
    const int fr_m = lane & 15;
    const int fr_k = (lane >> 4) * 8;
    const int wm = wave * 32;

    const short* gsrc[6];
    short* ldst[6];
#pragma unroll
    for (int j = 0; j < 6; ++j) {
        int c = wave * 6 + j;
        if (c < 16) {
            int kt = c >> 3, rg = c & 7;
            gsrc[j] = A + (size_t)(bm + rg * 16 + st_row) * K + kt * 32 + st_col;
            ldst[j] = &As[kt][(rg * 16) * 32];
        } else {
            int cb = c - 16;
            int kt = cb >> 2, rg = cb & 3;
            gsrc[j] = Bt + (size_t)(bn + rg * 16 + st_row) * K + kt * 32 + st_col;
            ldst[j] = &Bs[kt][(rg * 16) * 32];
        }
    }

    f32x4 acc[2][4];
#pragma unroll
    for (int mi = 0; mi < 2; ++mi)
#pragma unroll
        for (int ni = 0; ni < 4; ++ni) acc[mi][ni] = (f32x4){0.f, 0.f, 0.f, 0.f};

    for (int k0 = 0; k0 < K; k0 += 64) {
#pragma unroll
        for (int j = 0; j < 6; ++j) gload_lds16(gsrc[j] + k0, ldst[j]);
        __syncthreads();

#pragma unroll
        for (int kt = 0; kt < 2; ++kt) {
            bf16x8 af[2], bf[4];
#pragma unroll
            for (int mi = 0; mi < 2; ++mi)
                af[mi] = *reinterpret_cast<const bf16x8*>(
                    &As[kt][(wm + mi * 16 + fr_m) * 32 + fr_k]);
#pragma unroll
            for (int ni = 0; ni < 4; ++ni)
                bf[ni] = *reinterpret_cast<const bf16x8*>(
                    &Bs[kt][(ni * 16 + fr_m) * 32 + fr_k]);
#pragma unroll
            for (int mi = 0; mi < 2; ++mi)
#pragma unroll
                for (int ni = 0; ni < 4; ++ni)
                    acc[mi][ni] = __builtin_amdgcn_mfma_f32_16x16x32_bf16(
                        af[mi], bf[ni], acc[mi][ni], 0, 0, 0);
        }
        __syncthreads();
    }

    float bv[4];
#pragma unroll
    for (int ni = 0; ni < 4; ++ni)
        bv[ni] = bias[bn + ni * 16 + (lane & 15)];
#pragma unroll
    for (int mi = 0; mi < 2; ++mi) {
        int rbase = bm + wm + mi * 16 + (lane >> 4) * 4;
#pragma unroll
        for (int r = 0; r < 4; ++r) {
            size_t off = (size_t)(rbase + r) * N + bn + (lane & 15);
#pragma unroll
            for (int ni = 0; ni < 4; ++ni) {
                float val = acc[mi][ni][r] + bv[ni];
                if (BF16OUT) ((short*)Cv)[off + ni * 16] = f2bf(val);
                else         ((float*)Cv)[off + ni * 16] = val;
            }
        }
    }
}

// ---------------------------------------------------------------------------
// bf16 MFMA GEMM, 64x64 tile, BK=64 (high-TLP variant for small-N GEMM2).
// 768 blocks at N=768/M=4096: 3 blocks/CU, all resident. fp32 out.
// ---------------------------------------------------------------------------
__global__ __launch_bounds__(256) void gemm_bf16_64(
    const short* __restrict__ A, const short* __restrict__ Bt,
    const float* __restrict__ bias, float* __restrict__ C,
    int M, int N, int K)
{
    __shared__ short As[2][64 * 32];
    __shared__ short Bs[2][64 * 32];

    const int tid  = threadIdx.x;
    const int wave = tid >> 6;
    const int lane = tid & 63;
    const int bm = blockIdx.y * 64;
    const int bn = blockIdx.x * 64;

    const int st_row = lane >> 2;
    const int st_col = (lane & 3) * 8;
    const int fr_m = lane & 15;
    const int fr_k = (lane >> 4) * 8;
    const int wm = wave * 16;

    const short* gsrc[4];
    short* ldst[4];
#pragma unroll
    for (int j = 0; j < 4; ++j) {
        int c = wave * 4 + j;
        if (c < 8) {
            int kt = c >> 2, rg = c & 3;
            gsrc[j] = A + (size_t)(bm + rg * 16 + st_row) * K + kt * 32 + st_col;
            ldst[j] = &As[kt][(rg * 16) * 32];
        } else {
            int cb = c - 8;
            int kt = cb >> 2, rg = cb & 3;
            gsrc[j] = Bt + (size_t)(bn + rg * 16 + st_row) * K + kt * 32 + st_col;
            ldst[j] = &Bs[kt][(rg * 16) * 32];
        }
    }

    f32x4 acc[4];
#pragma unroll
    for (int ni = 0; ni < 4; ++ni) acc[ni] = (f32x4){0.f, 0.f, 0.f, 0.f};

    for (int k0 = 0; k0 < K; k0 += 64) {
#pragma unroll
        for (int j = 0; j < 4; ++j) gload_lds16(gsrc[j] + k0, ldst[j]);
        __syncthreads();

#pragma unroll
        for (int kt = 0; kt < 2; ++kt) {
            bf16x8 af = *reinterpret_cast<const bf16x8*>(
                &As[kt][(wm + fr_m) * 32 + fr_k]);
#pragma unroll
            for (int ni = 0; ni < 4; ++ni) {
                bf16x8 bf = *reinterpret_cast<const bf16x8*>(
                    &Bs[kt][(ni * 16 + fr_m) * 32 + fr_k]);
                acc[ni] = __builtin_amdgcn_mfma_f32_16x16x32_bf16(
                    af, bf, acc[ni], 0, 0, 0);
            }
        }
        __syncthreads();
    }

    float bv[4];
#pragma unroll
    for (int ni = 0; ni < 4; ++ni)
        bv[ni] = bias[bn + ni * 16 + (lane & 15)];
    int rbase = bm + wm + (lane >> 4) * 4;
#pragma unroll
    for (int r = 0; r < 4; ++r) {
        size_t off = (size_t)(rbase + r) * N + bn + (lane & 15);
#pragma unroll
        for (int ni = 0; ni < 4; ++ni)
            C[off + ni * 16] = acc[ni][r] + bv[ni];
    }
}

// ---------------------------------------------------------------------------
// Windowed trittention, wave-private softmax + pair-tree pm reduction.
// __launch_bounds__(256,6): cap VGPR at 85 -> 6 blocks/CU (12 = 2 rounds).
// ---------------------------------------------------------------------------
__global__ __launch_bounds__(256, 6) void attn_kernel(
    const short* __restrict__ abcde, short* __restrict__ z)
{
    const int blk = blockIdx.x;
    const int n  = blk & (NWIN - 1);
    const int bh = blk >> 7;
    const int b  = bh / NHEADS;
    const int h  = bh % NHEADS;

    __shared__ short sc[WIN * PAD_K];
    __shared__ short sa[WW * PAD_K];
    __shared__ short sb[WW * PAD_K];
    __shared__ short sd[WW * PAD_K];
    __shared__ short se[WW * PAD_K];
    __shared__ short epA[WIN * PAD_K];     // [i][0..31]=pm, [32..63]=pl (bf16, unnorm)
    __shared__ float sinv[WIN];

    const int tid = threadIdx.x;
    const size_t rowbase = ((size_t)b * T_SEQ) * NABCDE;
    const int hd = h * DHEAD;

    // ---- staging
    if (tid < 128) {
        int row = tid >> 3, ch = (tid & 7) * 8;
        *reinterpret_cast<uint4*>(&sc[row * PAD_K + ch]) =
            *reinterpret_cast<const uint4*>(
                &abcde[rowbase + (size_t)(n * WIN + row) * NABCDE + 2 * DMODEL + hd + ch]);
    }
    {
        int row = tid >> 3, ch = (tid & 7) * 8;
        int t = n * WIN - WIN + row;
        uint4 va = {0u, 0u, 0u, 0u}, vb = va, vd = va, ve = va;
        if (t >= 0) {
            size_t base = rowbase + (size_t)t * NABCDE + hd + ch;
            va = *reinterpret_cast<const uint4*>(&abcde[base + 0 * DMODEL]);
            vb = *reinterpret_cast<const uint4*>(&abcde[base + 1 * DMODEL]);
            vd = *reinterpret_cast<const uint4*>(&abcde[base + 3 * DMODEL]);
            ve = *reinterpret_cast<const uint4*>(&abcde[base + 4 * DMODEL]);
        }
        *reinterpret_cast<uint4*>(&sa[row * PAD_K + ch]) = va;
        *reinterpret_cast<uint4*>(&sb[row * PAD_K + ch]) = vb;
        *reinterpret_cast<uint4*>(&sd[row * PAD_K + ch]) = vd;
        *reinterpret_cast<uint4*>(&se[row * PAD_K + ch]) = ve;
    }
    __syncthreads();   // B1

    const int wv = tid >> 6;
    const int lane = tid & 63;
    const int lc = lane & 15;
    const int ko = lane >> 4;

    // ---- c fragment pre-split into (lo,hi) float2 pairs; b fragments raw
    f32x2 c2[2][4];
    bf16x8 bfrag[2][2];
#pragma unroll
    for (int kt = 0; kt < 2; ++kt) {
        union { bf16x8 v; unsigned u[4]; } Cf;
        Cf.v = *reinterpret_cast<const bf16x8*>(
            &sc[(wv * 4 + (lc & 3)) * PAD_K + kt * 32 + ko * 8]);
#pragma unroll
        for (int j = 0; j < 4; ++j) {
            c2[kt][j] = (f32x2){__uint_as_float(Cf.u[j] << 16),
                                __uint_as_float(Cf.u[j] & 0xffff0000u)};
        }
        bfrag[0][kt] = *reinterpret_cast<const bf16x8*>(&sb[lc * PAD_K + kt * 32 + ko * 8]);
        bfrag[1][kt] = *reinterpret_cast<const bf16x8*>(&sb[(16 + lc) * PAD_K + kt * 32 + ko * 8]);
    }

    f32x4 acc[8][2];
#pragma unroll
    for (int mt = 0; mt < 8; ++mt) {
        acc[mt][0] = (f32x4){0.f, 0.f, 0.f, 0.f};
        acc[mt][1] = (f32x4){0.f, 0.f, 0.f, 0.f};
    }
#pragma unroll
    for (int mt = 0; mt < 8; ++mt) {
#pragma unroll
        for (int kt = 0; kt < 2; ++kt) {
            union { bf16x8 v; unsigned u[4]; } Ar, Rf;
            Ar.v = *reinterpret_cast<const bf16x8*>(
                &sa[(mt * 4 + (lc >> 2)) * PAD_K + kt * 32 + ko * 8]);
#pragma unroll
            for (int j = 0; j < 4; ++j) {
                f32x2 y = (f32x2){__uint_as_float(Ar.u[j] << 16),
                                  __uint_as_float(Ar.u[j] & 0xffff0000u)};
                f32x2 p = c2[kt][j] * y;          // -> v_pk_mul_f32
                Rf.u[j] = __builtin_amdgcn_perm(
                    __float_as_uint(p[1]), __float_as_uint(p[0]), 0x07060302);
            }
            acc[mt][0] = __builtin_amdgcn_mfma_f32_16x16x32_bf16(Rf.v, bfrag[0][kt], acc[mt][0], 0, 0, 0);
            acc[mt][1] = __builtin_amdgcn_mfma_f32_16x16x32_bf16(Rf.v, bfrag[1][kt], acc[mt][1], 0, 0, 0);
        }
    }

    // ---- mask + per-query max
    const int nbase = n * WIN;
    int bbl_h[2];
#pragma unroll
    for (int lt = 0; lt < 2; ++lt) {
        int l = lt * 16 + lc;
        bbl_h[lt] = (n == 0 && l < WIN) ? 0 : (nbase - WIN + l);
    }
    float mx[4] = {-3.4e38f, -3.4e38f, -3.4e38f, -3.4e38f};
#pragma unroll
    for (int mt = 0; mt < 8; ++mt) {
        int m = mt * 4 + ko;
        int bbm = (n == 0 && m < WIN) ? 0 : (nbase - WIN + m);
#pragma unroll
        for (int lt = 0; lt < 2; ++lt) {
            bool mgt = bbl_h[lt] > bbm;
#pragma unroll
            for (int reg = 0; reg < 4; ++reg) {
                int tq = nbase + wv * 4 + reg;
                float v = acc[mt][lt][reg];
                bool keep = (tq >= bbl_h[lt]) && mgt;
                if (!keep || v == 0.0f) v = IGNORE_V;
                acc[mt][lt][reg] = v;
                mx[reg] = fmaxf(mx[reg], v);
            }
        }
    }
#pragma unroll
    for (int reg = 0; reg < 4; ++reg) {
#pragma unroll
        for (int off = 1; off < 64; off <<= 1)
            mx[reg] = fmaxf(mx[reg], __shfl_xor(mx[reg], off, 64));
    }

    // ---- exp2-folded softmax numerator
    float c0[4];
#pragma unroll
    for (int reg = 0; reg < 4; ++reg) c0[reg] = -mx[reg] * L2E64;
#pragma unroll
    for (int mt = 0; mt < 8; ++mt)
#pragma unroll
        for (int lt = 0; lt < 2; ++lt)
#pragma unroll
            for (int reg = 0; reg < 4; ++reg)
                acc[mt][lt][reg] = exp2f(fmaf(acc[mt][lt][reg], L2E64, c0[reg]));

    // ---- pl (col-marginal over m) + epA cols 32..63; keep plv for sm
    float plv[2][4];
#pragma unroll
    for (int lt = 0; lt < 2; ++lt) {
#pragma unroll
        for (int reg = 0; reg < 4; ++reg) {
            float p = acc[0][lt][reg];
#pragma unroll
            for (int mt = 1; mt < 8; ++mt) p += acc[mt][lt][reg];
            p += __shfl_xor(p, 16, 64);
            p += __shfl_xor(p, 32, 64);
            plv[lt][reg] = p;
        }
        float w  = (ko & 1) ? plv[lt][1] : plv[lt][0];
        float w2 = (ko & 1) ? plv[lt][3] : plv[lt][2];
        float ww = (ko & 2) ? w2 : w;
        epA[(wv * 4 + ko) * PAD_K + 32 + lt * 16 + lc] = f2bf(ww);
    }

    // ---- sm[i] = sum_l pl[i][l]
    {
        float s[4];
#pragma unroll
        for (int reg = 0; reg < 4; ++reg) {
            float t = plv[0][reg] + plv[1][reg];
            t += __shfl_xor(t, 1, 64);
            t += __shfl_xor(t, 2, 64);
            t += __shfl_xor(t, 4, 64);
            t += __shfl_xor(t, 8, 64);
            s[reg] = t;
        }
        if (lane == 0) {
#pragma unroll
            for (int reg = 0; reg < 4; ++reg) sinv[wv * 4 + reg] = 1.0f / s[reg];
        }
    }

    // ---- pm via pair-tree over lc; write epA cols 0..31
    {
        float v8[8][4];
#pragma unroll
        for (int mt = 0; mt < 8; ++mt)
#pragma unroll
            for (int reg = 0; reg < 4; ++reg)
                v8[mt][reg] = acc[mt][0][reg] + acc[mt][1][reg];

        const bool s0 = lane & 1, s1 = lane & 2, s2 = lane & 4, s3 = lane & 8;
        float r1[4][4];
#pragma unroll
        for (int m2 = 0; m2 < 4; ++m2)
#pragma unroll
            for (int reg = 0; reg < 4; ++reg) {
                float u = v8[2 * m2][reg], w = v8[2 * m2 + 1][reg];
                float a = s0 ? w : u;
                float s = s0 ? u : w;
                r1[m2][reg] = a + __shfl_xor(s, 1, 64);
            }
        float r2[2][4];
#pragma unroll
        for (int m4 = 0; m4 < 2; ++m4)
#pragma unroll
            for (int reg = 0; reg < 4; ++reg) {
                float u = r1[2 * m4][reg], w = r1[2 * m4 + 1][reg];
                float a = s1 ? w : u;
                float s = s1 ? u : w;
                r2[m4][reg] = a + __shfl_xor(s, 2, 64);
            }
        float r3[4];
#pragma unroll
        for (int reg = 0; reg < 4; ++reg) {
            float u = r2[0][reg], w = r2[1][reg];
            float a = s2 ? w : u;
            float s = s2 ? u : w;
            r3[reg] = a + __shfl_xor(s, 4, 64);
        }
        float a0 = s3 ? r3[1] : r3[0];
        float q0 = s3 ? r3[0] : r3[1];
        float g0 = a0 + __shfl_xor(q0, 8, 64);
        float a1 = s3 ? r3[3] : r3[2];
        float q1 = s3 ? r3[2] : r3[3];
        float g1 = a1 + __shfl_xor(q1, 8, 64);

        int mcol = (lc & 7) * 4 + ko;
        int ib = wv * 4 + (lc >> 3);
        epA[ib * PAD_K + mcol]       = f2bf(g0);
        epA[(ib + 2) * PAD_K + mcol] = f2bf(g1);
    }

    // ---- epilogue B-frags from sd/se (pre-barrier; dd = wv*16+lc)
    const int dd = wv * 16 + lc;
    bf16x8 bd, be;
    {
        unsigned dv[8], ev[8];
#pragma unroll
        for (int j = 0; j < 8; ++j) {
            dv[j] = *reinterpret_cast<const unsigned short*>(&sd[(ko * 8 + j) * PAD_K + dd]);
            ev[j] = *reinterpret_cast<const unsigned short*>(&se[(ko * 8 + j) * PAD_K + dd]);
        }
        union { unsigned u[4]; bf16x8 v; } td, te;
#pragma unroll
        for (int j = 0; j < 4; ++j) {
            td.u[j] = __builtin_amdgcn_perm(dv[2 * j + 1], dv[2 * j], 0x05040100);
            te.u[j] = __builtin_amdgcn_perm(ev[2 * j + 1], ev[2 * j], 0x05040100);
        }
        bd = td.v; be = te.v;
    }
    __syncthreads();   // B2

    // ---- cooperative epilogue MFMA
    bf16x8 apm = *reinterpret_cast<const bf16x8*>(&epA[lc * PAD_K + ko * 8]);
    bf16x8 apl = *reinterpret_cast<const bf16x8*>(&epA[lc * PAD_K + 32 + ko * 8]);
    f32x4 zacc = (f32x4){0.f, 0.f, 0.f, 0.f};
    zacc = __builtin_amdgcn_mfma_f32_16x16x32_bf16(apm, bd, zacc, 0, 0, 0);
    zacc = __builtin_amdgcn_mfma_f32_16x16x32_bf16(apl, be, zacc, 0, 0, 0);

#pragma unroll
    for (int reg = 0; reg < 4; ++reg) {
        int i = ko * 4 + reg;
        z[((size_t)b * T_SEQ + nbase + i) * (NHEADS * DHEAD) + hd + dd] =
            f2bf(zacc[reg] * sinv[i]);
    }
}

// ---------------------------------------------------------------------------
extern "C" void kernel_launch(void* const* d_in, const int* in_sizes, int n_in,
                              void* d_out, int out_size, void* d_ws, size_t ws_size,
                              hipStream_t stream) {
    const float* x        = (const float*)d_in[0];
    const float* W_abcde  = (const float*)d_in[1];
    const float* b_abcde  = (const float*)d_in[2];
    const float* W_O      = (const float*)d_in[3];
    const float* b_O      = (const float*)d_in[4];
    float* out = (float*)d_out;

    char* ws = (char*)d_ws;
    short* abcde = (short*)ws;                                  // 4096x3840 bf16 (31.5 MB)
    short* xb    = (short*)(ws + (size_t)31457280);             // 4096x768 bf16, reused as zb
    short* Wt    = (short*)(ws + (size_t)31457280 + 6291456);   // 3840x768 bf16
    short* WOt   = (short*)(ws + (size_t)31457280 + 6291456 + 5898240); // 768x768 bf16
    short* zb    = xb;

    const int M = 2 * T_SEQ;  // 4096

    prep_kernel<<<dim3(4992), dim3(256), 0, stream>>>(
        x, W_abcde, W_O, xb, Wt, WOt);

    gemm_bf16_n64<true><<<dim3(NABCDE / 64, M / 128), dim3(256), 0, stream>>>(
        xb, Wt, b_abcde, (void*)abcde, M, NABCDE, DMODEL);

    attn_kernel<<<dim3(2 * NHEADS * NWIN), dim3(256), 0, stream>>>(abcde, zb);

    gemm_bf16_64<<<dim3(DMODEL / 64, M / 64), dim3(256), 0, stream>>>(
        zb, WOt, b_O, out, M, DMODEL, DMODEL);
}

// Round 9
// 172.131 us; speedup vs baseline: 1.1384x; 1.1384x over previous
//
#include <hip/hip_runtime.h>

#define T_SEQ   2048
#define NHEADS  12
#define DHEAD   64
#define WIN     16
#define WW      32
#define NWIN    128
#define DMODEL  768
#define NABCDE  3840
#define IGNORE_V (-1.0e6f)
#define PAD_K   72          // bf16 LDS row stride (144 B, 16B-aligned)
#define L2E64   0.022542110013890053f   // log2(e)/64

typedef float f32x4 __attribute__((ext_vector_type(4)));
typedef float f32x2 __attribute__((ext_vector_type(2)));
typedef short bf16x8 __attribute__((ext_vector_type(8)));

__device__ __forceinline__ short f2bf(float f) {
    unsigned u = __float_as_uint(f);
    unsigned r = (u + 0x7FFF + ((u >> 16) & 1)) >> 16;   // RNE
    return (short)r;
}

__device__ __forceinline__ void gload_lds16(const short* g, short* l) {
    __builtin_amdgcn_global_load_lds(
        (const __attribute__((address_space(1))) void*)g,
        (__attribute__((address_space(3))) void*)l,
        16, 0, 0);
}

// ---------------------------------------------------------------------------
// merged prep: [0,1536) cast x -> xb; [1536,4416) transpose W_abcde -> Wt;
// [4416,4992) transpose W_O -> WOt.
// ---------------------------------------------------------------------------
__global__ __launch_bounds__(256) void prep_kernel(
    const float* __restrict__ x, const float* __restrict__ W_abcde,
    const float* __restrict__ W_O,
    short* __restrict__ xb, short* __restrict__ Wt, short* __restrict__ WOt)
{
    __shared__ float tile[32][33];
    const int blk = blockIdx.x;
    const int tid = threadIdx.x;

    if (blk < 1536) {
        int i = (blk * 256 + tid) * 8;
        float4 a = *reinterpret_cast<const float4*>(&x[i]);
        float4 b = *reinterpret_cast<const float4*>(&x[i + 4]);
        union { short s[8]; uint4 u; } r;
        r.s[0] = f2bf(a.x); r.s[1] = f2bf(a.y); r.s[2] = f2bf(a.z); r.s[3] = f2bf(a.w);
        r.s[4] = f2bf(b.x); r.s[5] = f2bf(b.y); r.s[6] = f2bf(b.z); r.s[7] = f2bf(b.w);
        *reinterpret_cast<uint4*>(&xb[i]) = r.u;
        return;
    }
    const float* W; short* Wo; int N, bx, by;
    if (blk < 4416) {
        int t = blk - 1536;
        W = W_abcde; Wo = Wt; N = NABCDE;
        bx = (t % 120) * 32; by = (t / 120) * 32;
    } else {
        int t = blk - 4416;
        W = W_O; Wo = WOt; N = DMODEL;
        bx = (t % 24) * 32; by = (t / 24) * 32;
    }
    const int tx = tid & 31, ty = tid >> 5;
#pragma unroll
    for (int r = 0; r < 32; r += 8)
        tile[ty + r][tx] = W[(size_t)(by + ty + r) * N + bx + tx];
    __syncthreads();
#pragma unroll
    for (int r = 0; r < 32; r += 8)
        Wo[(size_t)(bx + ty + r) * DMODEL + by + tx] = f2bf(tile[tx][ty + r]);
}

// ---------------------------------------------------------------------------
// bf16 MFMA GEMM, 128x64 tile, BK=64 dual 32-wide LDS buffers, balanced
// staging (24 glds chunks, 6 per wave). BF16OUT selects output type.
// ---------------------------------------------------------------------------
template <bool BF16OUT>
__global__ __launch_bounds__(256) void gemm_bf16_n64(
    const short* __restrict__ A, const short* __restrict__ Bt,
    const float* __restrict__ bias, void* __restrict__ Cv,
    int M, int N, int K)
{
    __shared__ short As[2][128 * 32];
    __shared__ short Bs[2][64 * 32];

    const int tid  = threadIdx.x;
    const int wave = tid >> 6;
    const int lane = tid & 63;
    const int bm = blockIdx.y * 128;
    const int bn = blockIdx.x * 64;

    const int st_row = lane >> 2;
    const int st_col = (lane & 3) * 8;
    const int fr_m = lane & 15;
    const int fr_k = (lane >> 4) * 8;
    const int wm = wave * 32;

    const short* gsrc[6];
    short* ldst[6];
#pragma unroll
    for (int j = 0; j < 6; ++j) {
        int c = wave * 6 + j;
        if (c < 16) {
            int kt = c >> 3, rg = c & 7;
            gsrc[j] = A + (size_t)(bm + rg * 16 + st_row) * K + kt * 32 + st_col;
            ldst[j] = &As[kt][(rg * 16) * 32];
        } else {
            int cb = c - 16;
            int kt = cb >> 2, rg = cb & 3;
            gsrc[j] = Bt + (size_t)(bn + rg * 16 + st_row) * K + kt * 32 + st_col;
            ldst[j] = &Bs[kt][(rg * 16) * 32];
        }
    }

    f32x4 acc[2][4];
#pragma unroll
    for (int mi = 0; mi < 2; ++mi)
#pragma unroll
        for (int ni = 0; ni < 4; ++ni) acc[mi][ni] = (f32x4){0.f, 0.f, 0.f, 0.f};

    for (int k0 = 0; k0 < K; k0 += 64) {
#pragma unroll
        for (int j = 0; j < 6; ++j) gload_lds16(gsrc[j] + k0, ldst[j]);
        __syncthreads();

#pragma unroll
        for (int kt = 0; kt < 2; ++kt) {
            bf16x8 af[2], bf[4];
#pragma unroll
            for (int mi = 0; mi < 2; ++mi)
                af[mi] = *reinterpret_cast<const bf16x8*>(
                    &As[kt][(wm + mi * 16 + fr_m) * 32 + fr_k]);
#pragma unroll
            for (int ni = 0; ni < 4; ++ni)
                bf[ni] = *reinterpret_cast<const bf16x8*>(
                    &Bs[kt][(ni * 16 + fr_m) * 32 + fr_k]);
#pragma unroll
            for (int mi = 0; mi < 2; ++mi)
#pragma unroll
                for (int ni = 0; ni < 4; ++ni)
                    acc[mi][ni] = __builtin_amdgcn_mfma_f32_16x16x32_bf16(
                        af[mi], bf[ni], acc[mi][ni], 0, 0, 0);
        }
        __syncthreads();
    }

    float bv[4];
#pragma unroll
    for (int ni = 0; ni < 4; ++ni)
        bv[ni] = bias[bn + ni * 16 + (lane & 15)];
#pragma unroll
    for (int mi = 0; mi < 2; ++mi) {
        int rbase = bm + wm + mi * 16 + (lane >> 4) * 4;
#pragma unroll
        for (int r = 0; r < 4; ++r) {
            size_t off = (size_t)(rbase + r) * N + bn + (lane & 15);
#pragma unroll
            for (int ni = 0; ni < 4; ++ni) {
                float val = acc[mi][ni][r] + bv[ni];
                if (BF16OUT) ((short*)Cv)[off + ni * 16] = f2bf(val);
                else         ((float*)Cv)[off + ni * 16] = val;
            }
        }
    }
}

// ---------------------------------------------------------------------------
// bf16 MFMA GEMM, 64x64 tile, BK=64 (high-TLP variant for small-N GEMM2).
// ---------------------------------------------------------------------------
__global__ __launch_bounds__(256) void gemm_bf16_64(
    const short* __restrict__ A, const short* __restrict__ Bt,
    const float* __restrict__ bias, float* __restrict__ C,
    int M, int N, int K)
{
    __shared__ short As[2][64 * 32];
    __shared__ short Bs[2][64 * 32];

    const int tid  = threadIdx.x;
    const int wave = tid >> 6;
    const int lane = tid & 63;
    const int bm = blockIdx.y * 64;
    const int bn = blockIdx.x * 64;

    const int st_row = lane >> 2;
    const int st_col = (lane & 3) * 8;
    const int fr_m = lane & 15;
    const int fr_k = (lane >> 4) * 8;
    const int wm = wave * 16;

    const short* gsrc[4];
    short* ldst[4];
#pragma unroll
    for (int j = 0; j < 4; ++j) {
        int c = wave * 4 + j;
        if (c < 8) {
            int kt = c >> 2, rg = c & 3;
            gsrc[j] = A + (size_t)(bm + rg * 16 + st_row) * K + kt * 32 + st_col;
            ldst[j] = &As[kt][(rg * 16) * 32];
        } else {
            int cb = c - 8;
            int kt = cb >> 2, rg = cb & 3;
            gsrc[j] = Bt + (size_t)(bn + rg * 16 + st_row) * K + kt * 32 + st_col;
            ldst[j] = &Bs[kt][(rg * 16) * 32];
        }
    }

    f32x4 acc[4];
#pragma unroll
    for (int ni = 0; ni < 4; ++ni) acc[ni] = (f32x4){0.f, 0.f, 0.f, 0.f};

    for (int k0 = 0; k0 < K; k0 += 64) {
#pragma unroll
        for (int j = 0; j < 4; ++j) gload_lds16(gsrc[j] + k0, ldst[j]);
        __syncthreads();

#pragma unroll
        for (int kt = 0; kt < 2; ++kt) {
            bf16x8 af = *reinterpret_cast<const bf16x8*>(
                &As[kt][(wm + fr_m) * 32 + fr_k]);
#pragma unroll
            for (int ni = 0; ni < 4; ++ni) {
                bf16x8 bf = *reinterpret_cast<const bf16x8*>(
                    &Bs[kt][(ni * 16 + fr_m) * 32 + fr_k]);
                acc[ni] = __builtin_amdgcn_mfma_f32_16x16x32_bf16(
                    af, bf, acc[ni], 0, 0, 0);
            }
        }
        __syncthreads();
    }

    float bv[4];
#pragma unroll
    for (int ni = 0; ni < 4; ++ni)
        bv[ni] = bias[bn + ni * 16 + (lane & 15)];
    int rbase = bm + wm + (lane >> 4) * 4;
#pragma unroll
    for (int r = 0; r < 4; ++r) {
        size_t off = (size_t)(rbase + r) * N + bn + (lane & 15);
#pragma unroll
        for (int ni = 0; ni < 4; ++ni)
            C[off + ni * 16] = acc[ni][r] + bv[ni];
    }
}

// ---------------------------------------------------------------------------
// Windowed trittention, wave-private softmax + pair-tree pm reduction.
// No launch-bounds cap (r8 showed a cap spills the unified VGPR+AGPR file).
// ---------------------------------------------------------------------------
__global__ __launch_bounds__(256) void attn_kernel(
    const short* __restrict__ abcde, short* __restrict__ z)
{
    const int blk = blockIdx.x;
    const int n  = blk & (NWIN - 1);
    const int bh = blk >> 7;
    const int b  = bh / NHEADS;
    const int h  = bh % NHEADS;

    __shared__ short sc[WIN * PAD_K];
    __shared__ short sa[WW * PAD_K];
    __shared__ short sb[WW * PAD_K];
    __shared__ short sd[WW * PAD_K];
    __shared__ short se[WW * PAD_K];
    __shared__ short epA[WIN * PAD_K];     // [i][0..31]=pm, [32..63]=pl (bf16, unnorm)
    __shared__ float sinv[WIN];

    const int tid = threadIdx.x;
    const size_t rowbase = ((size_t)b * T_SEQ) * NABCDE;
    const int hd = h * DHEAD;

    // ---- staging
    if (tid < 128) {
        int row = tid >> 3, ch = (tid & 7) * 8;
        *reinterpret_cast<uint4*>(&sc[row * PAD_K + ch]) =
            *reinterpret_cast<const uint4*>(
                &abcde[rowbase + (size_t)(n * WIN + row) * NABCDE + 2 * DMODEL + hd + ch]);
    }
    {
        int row = tid >> 3, ch = (tid & 7) * 8;
        int t = n * WIN - WIN + row;
        uint4 va = {0u, 0u, 0u, 0u}, vb = va, vd = va, ve = va;
        if (t >= 0) {
            size_t base = rowbase + (size_t)t * NABCDE + hd + ch;
            va = *reinterpret_cast<const uint4*>(&abcde[base + 0 * DMODEL]);
            vb = *reinterpret_cast<const uint4*>(&abcde[base + 1 * DMODEL]);
            vd = *reinterpret_cast<const uint4*>(&abcde[base + 3 * DMODEL]);
            ve = *reinterpret_cast<const uint4*>(&abcde[base + 4 * DMODEL]);
        }
        *reinterpret_cast<uint4*>(&sa[row * PAD_K + ch]) = va;
        *reinterpret_cast<uint4*>(&sb[row * PAD_K + ch]) = vb;
        *reinterpret_cast<uint4*>(&sd[row * PAD_K + ch]) = vd;
        *reinterpret_cast<uint4*>(&se[row * PAD_K + ch]) = ve;
    }
    __syncthreads();   // B1

    const int wv = tid >> 6;
    const int lane = tid & 63;
    const int lc = lane & 15;
    const int ko = lane >> 4;

    // ---- c fragment pre-split into (lo,hi) float2 pairs; b fragments raw
    f32x2 c2[2][4];
    bf16x8 bfrag[2][2];
#pragma unroll
    for (int kt = 0; kt < 2; ++kt) {
        union { bf16x8 v; unsigned u[4]; } Cf;
        Cf.v = *reinterpret_cast<const bf16x8*>(
            &sc[(wv * 4 + (lc & 3)) * PAD_K + kt * 32 + ko * 8]);
#pragma unroll
        for (int j = 0; j < 4; ++j) {
            c2[kt][j] = (f32x2){__uint_as_float(Cf.u[j] << 16),
                                __uint_as_float(Cf.u[j] & 0xffff0000u)};
        }
        bfrag[0][kt] = *reinterpret_cast<const bf16x8*>(&sb[lc * PAD_K + kt * 32 + ko * 8]);
        bfrag[1][kt] = *reinterpret_cast<const bf16x8*>(&sb[(16 + lc) * PAD_K + kt * 32 + ko * 8]);
    }

    f32x4 acc[8][2];
#pragma unroll
    for (int mt = 0; mt < 8; ++mt) {
        acc[mt][0] = (f32x4){0.f, 0.f, 0.f, 0.f};
        acc[mt][1] = (f32x4){0.f, 0.f, 0.f, 0.f};
    }
#pragma unroll
    for (int mt = 0; mt < 8; ++mt) {
#pragma unroll
        for (int kt = 0; kt < 2; ++kt) {
            union { bf16x8 v; unsigned u[4]; } Ar, Rf;
            Ar.v = *reinterpret_cast<const bf16x8*>(
                &sa[(mt * 4 + (lc >> 2)) * PAD_K + kt * 32 + ko * 8]);
#pragma unroll
            for (int j = 0; j < 4; ++j) {
                f32x2 y = (f32x2){__uint_as_float(Ar.u[j] << 16),
                                  __uint_as_float(Ar.u[j] & 0xffff0000u)};
                f32x2 p = c2[kt][j] * y;          // -> v_pk_mul_f32
                Rf.u[j] = __builtin_amdgcn_perm(
                    __float_as_uint(p[1]), __float_as_uint(p[0]), 0x07060302);
            }
            acc[mt][0] = __builtin_amdgcn_mfma_f32_16x16x32_bf16(Rf.v, bfrag[0][kt], acc[mt][0], 0, 0, 0);
            acc[mt][1] = __builtin_amdgcn_mfma_f32_16x16x32_bf16(Rf.v, bfrag[1][kt], acc[mt][1], 0, 0, 0);
        }
    }

    // ---- mask: keepL hoisted (8 cmps); zero-hack only for the padded
    //      window n==0 (block-uniform branch) — for n>0 an exact-0.0 score
    //      is measure-zero and masked regions are already IGNORE.
    const int nbase = n * WIN;
    int bbl_h[2];
    bool keepL[2][4];
#pragma unroll
    for (int lt = 0; lt < 2; ++lt) {
        int l = lt * 16 + lc;
        bbl_h[lt] = (n == 0 && l < WIN) ? 0 : (nbase - WIN + l);
#pragma unroll
        for (int reg = 0; reg < 4; ++reg)
            keepL[lt][reg] = (nbase + wv * 4 + reg) >= bbl_h[lt];
    }
#pragma unroll
    for (int mt = 0; mt < 8; ++mt) {
        int m = mt * 4 + ko;
        int bbm = (n == 0 && m < WIN) ? 0 : (nbase - WIN + m);
#pragma unroll
        for (int lt = 0; lt < 2; ++lt) {
            bool mgt = bbl_h[lt] > bbm;
#pragma unroll
            for (int reg = 0; reg < 4; ++reg) {
                if (!(keepL[lt][reg] && mgt)) acc[mt][lt][reg] = IGNORE_V;
            }
        }
    }
    if (n == 0) {
#pragma unroll
        for (int mt = 0; mt < 8; ++mt)
#pragma unroll
            for (int lt = 0; lt < 2; ++lt)
#pragma unroll
                for (int reg = 0; reg < 4; ++reg)
                    if (acc[mt][lt][reg] == 0.0f) acc[mt][lt][reg] = IGNORE_V;
    }

    // ---- per-query max
    float mx[4] = {-3.4e38f, -3.4e38f, -3.4e38f, -3.4e38f};
#pragma unroll
    for (int mt = 0; mt < 8; ++mt)
#pragma unroll
        for (int lt = 0; lt < 2; ++lt)
#pragma unroll
            for (int reg = 0; reg < 4; ++reg)
                mx[reg] = fmaxf(mx[reg], acc[mt][lt][reg]);
#pragma unroll
    for (int reg = 0; reg < 4; ++reg) {
#pragma unroll
        for (int off = 1; off < 64; off <<= 1)
            mx[reg] = fmaxf(mx[reg], __shfl_xor(mx[reg], off, 64));
    }

    // ---- exp2-folded softmax numerator
    float c0[4];
#pragma unroll
    for (int reg = 0; reg < 4; ++reg) c0[reg] = -mx[reg] * L2E64;
#pragma unroll
    for (int mt = 0; mt < 8; ++mt)
#pragma unroll
        for (int lt = 0; lt < 2; ++lt)
#pragma unroll
            for (int reg = 0; reg < 4; ++reg)
                acc[mt][lt][reg] = exp2f(fmaf(acc[mt][lt][reg], L2E64, c0[reg]));

    // ---- pl (col-marginal over m) + epA cols 32..63; keep plv for sm
    float plv[2][4];
#pragma unroll
    for (int lt = 0; lt < 2; ++lt) {
#pragma unroll
        for (int reg = 0; reg < 4; ++reg) {
            float p = acc[0][lt][reg];
#pragma unroll
            for (int mt = 1; mt < 8; ++mt) p += acc[mt][lt][reg];
            p += __shfl_xor(p, 16, 64);
            p += __shfl_xor(p, 32, 64);
            plv[lt][reg] = p;
        }
        float w  = (ko & 1) ? plv[lt][1] : plv[lt][0];
        float w2 = (ko & 1) ? plv[lt][3] : plv[lt][2];
        float ww = (ko & 2) ? w2 : w;
        epA[(wv * 4 + ko) * PAD_K + 32 + lt * 16 + lc] = f2bf(ww);
    }

    // ---- sm[i] = sum_l pl[i][l]
    {
        float s[4];
#pragma unroll
        for (int reg = 0; reg < 4; ++reg) {
            float t = plv[0][reg] + plv[1][reg];
            t += __shfl_xor(t, 1, 64);
            t += __shfl_xor(t, 2, 64);
            t += __shfl_xor(t, 4, 64);
            t += __shfl_xor(t, 8, 64);
            s[reg] = t;
        }
        if (lane == 0) {
#pragma unroll
            for (int reg = 0; reg < 4; ++reg) sinv[wv * 4 + reg] = 1.0f / s[reg];
        }
    }

    // ---- pm via pair-tree over lc; write epA cols 0..31
    {
        float v8[8][4];
#pragma unroll
        for (int mt = 0; mt < 8; ++mt)
#pragma unroll
            for (int reg = 0; reg < 4; ++reg)
                v8[mt][reg] = acc[mt][0][reg] + acc[mt][1][reg];

        const bool s0 = lane & 1, s1 = lane & 2, s2 = lane & 4, s3 = lane & 8;
        float r1[4][4];
#pragma unroll
        for (int m2 = 0; m2 < 4; ++m2)
#pragma unroll
            for (int reg = 0; reg < 4; ++reg) {
                float u = v8[2 * m2][reg], w = v8[2 * m2 + 1][reg];
                float a = s0 ? w : u;
                float s = s0 ? u : w;
                r1[m2][reg] = a + __shfl_xor(s, 1, 64);
            }
        float r2[2][4];
#pragma unroll
        for (int m4 = 0; m4 < 2; ++m4)
#pragma unroll
            for (int reg = 0; reg < 4; ++reg) {
                float u = r1[2 * m4][reg], w = r1[2 * m4 + 1][reg];
                float a = s1 ? w : u;
                float s = s1 ? u : w;
                r2[m4][reg] = a + __shfl_xor(s, 2, 64);
            }
        float r3[4];
#pragma unroll
        for (int reg = 0; reg < 4; ++reg) {
            float u = r2[0][reg], w = r2[1][reg];
            float a = s2 ? w : u;
            float s = s2 ? u : w;
            r3[reg] = a + __shfl_xor(s, 4, 64);
        }
        float a0 = s3 ? r3[1] : r3[0];
        float q0 = s3 ? r3[0] : r3[1];
        float g0 = a0 + __shfl_xor(q0, 8, 64);
        float a1 = s3 ? r3[3] : r3[2];
        float q1 = s3 ? r3[2] : r3[3];
        float g1 = a1 + __shfl_xor(q1, 8, 64);

        int mcol = (lc & 7) * 4 + ko;
        int ib = wv * 4 + (lc >> 3);
        epA[ib * PAD_K + mcol]       = f2bf(g0);
        epA[(ib + 2) * PAD_K + mcol] = f2bf(g1);
    }

    // ---- epilogue B-frags from sd/se (pre-barrier; dd = wv*16+lc)
    const int dd = wv * 16 + lc;
    bf16x8 bd, be;
    {
        unsigned dv[8], ev[8];
#pragma unroll
        for (int j = 0; j < 8; ++j) {
            dv[j] = *reinterpret_cast<const unsigned short*>(&sd[(ko * 8 + j) * PAD_K + dd]);
            ev[j] = *reinterpret_cast<const unsigned short*>(&se[(ko * 8 + j) * PAD_K + dd]);
        }
        union { unsigned u[4]; bf16x8 v; } td, te;
#pragma unroll
        for (int j = 0; j < 4; ++j) {
            td.u[j] = __builtin_amdgcn_perm(dv[2 * j + 1], dv[2 * j], 0x05040100);
            te.u[j] = __builtin_amdgcn_perm(ev[2 * j + 1], ev[2 * j], 0x05040100);
        }
        bd = td.v; be = te.v;
    }
    __syncthreads();   // B2

    // ---- cooperative epilogue MFMA
    bf16x8 apm = *reinterpret_cast<const bf16x8*>(&epA[lc * PAD_K + ko * 8]);
    bf16x8 apl = *reinterpret_cast<const bf16x8*>(&epA[lc * PAD_K + 32 + ko * 8]);
    f32x4 zacc = (f32x4){0.f, 0.f, 0.f, 0.f};
    zacc = __builtin_amdgcn_mfma_f32_16x16x32_bf16(apm, bd, zacc, 0, 0, 0);
    zacc = __builtin_amdgcn_mfma_f32_16x16x32_bf16(apl, be, zacc, 0, 0, 0);

#pragma unroll
    for (int reg = 0; reg < 4; ++reg) {
        int i = ko * 4 + reg;
        z[((size_t)b * T_SEQ + nbase + i) * (NHEADS * DHEAD) + hd + dd] =
            f2bf(zacc[reg] * sinv[i]);
    }
}

// ---------------------------------------------------------------------------
extern "C" void kernel_launch(void* const* d_in, const int* in_sizes, int n_in,
                              void* d_out, int out_size, void* d_ws, size_t ws_size,
                              hipStream_t stream) {
    const float* x        = (const float*)d_in[0];
    const float* W_abcde  = (const float*)d_in[1];
    const float* b_abcde  = (const float*)d_in[2];
    const float* W_O      = (const float*)d_in[3];
    const float* b_O      = (const float*)d_in[4];
    float* out = (float*)d_out;

    char* ws = (char*)d_ws;
    short* abcde = (short*)ws;                                  // 4096x3840 bf16 (31.5 MB)
    short* xb    = (short*)(ws + (size_t)31457280);             // 4096x768 bf16, reused as zb
    short* Wt    = (short*)(ws + (size_t)31457280 + 6291456);   // 3840x768 bf16
    short* WOt   = (short*)(ws + (size_t)31457280 + 6291456 + 5898240); // 768x768 bf16
    short* zb    = xb;

    const int M = 2 * T_SEQ;  // 4096

    prep_kernel<<<dim3(4992), dim3(256), 0, stream>>>(
        x, W_abcde, W_O, xb, Wt, WOt);

    gemm_bf16_n64<true><<<dim3(NABCDE / 64, M / 128), dim3(256), 0, stream>>>(
        xb, Wt, b_abcde, (void*)abcde, M, NABCDE, DMODEL);

    attn_kernel<<<dim3(2 * NHEADS * NWIN), dim3(256), 0, stream>>>(abcde, zb);

    gemm_bf16_64<<<dim3(DMODEL / 64, M / 64), dim3(256), 0, stream>>>(
        zb, WOt, b_O, out, M, DMODEL, DMODEL);
}

// Round 10
// 168.836 us; speedup vs baseline: 1.1606x; 1.0195x over previous
//
#include <hip/hip_runtime.h>

#define T_SEQ   2048
#define NHEADS  12
#define DHEAD   64
#define WIN     16
#define WW      32
#define NWIN    128
#define DMODEL  768
#define NABCDE  3840
#define IGNORE_V (-1.0e6f)
#define PAD_K   72          // bf16 LDS row stride (144 B, 16B-aligned)
#define L2E64   0.022542110013890053f   // log2(e)/64

typedef float f32x4 __attribute__((ext_vector_type(4)));
typedef float f32x2 __attribute__((ext_vector_type(2)));
typedef short bf16x8 __attribute__((ext_vector_type(8)));

__device__ __forceinline__ short f2bf(float f) {
    unsigned u = __float_as_uint(f);
    unsigned r = (u + 0x7FFF + ((u >> 16) & 1)) >> 16;   // RNE
    return (short)r;
}

__device__ __forceinline__ void gload_lds16(const short* g, short* l) {
    __builtin_amdgcn_global_load_lds(
        (const __attribute__((address_space(1))) void*)g,
        (__attribute__((address_space(3))) void*)l,
        16, 0, 0);
}

// ---------------------------------------------------------------------------
// merged prep: [0,1536) cast x -> xb; [1536,4416) transpose W_abcde -> Wt;
// [4416,4992) transpose W_O -> WOt.
// ---------------------------------------------------------------------------
__global__ __launch_bounds__(256) void prep_kernel(
    const float* __restrict__ x, const float* __restrict__ W_abcde,
    const float* __restrict__ W_O,
    short* __restrict__ xb, short* __restrict__ Wt, short* __restrict__ WOt)
{
    __shared__ float tile[32][33];
    const int blk = blockIdx.x;
    const int tid = threadIdx.x;

    if (blk < 1536) {
        int i = (blk * 256 + tid) * 8;
        float4 a = *reinterpret_cast<const float4*>(&x[i]);
        float4 b = *reinterpret_cast<const float4*>(&x[i + 4]);
        union { short s[8]; uint4 u; } r;
        r.s[0] = f2bf(a.x); r.s[1] = f2bf(a.y); r.s[2] = f2bf(a.z); r.s[3] = f2bf(a.w);
        r.s[4] = f2bf(b.x); r.s[5] = f2bf(b.y); r.s[6] = f2bf(b.z); r.s[7] = f2bf(b.w);
        *reinterpret_cast<uint4*>(&xb[i]) = r.u;
        return;
    }
    const float* W; short* Wo; int N, bx, by;
    if (blk < 4416) {
        int t = blk - 1536;
        W = W_abcde; Wo = Wt; N = NABCDE;
        bx = (t % 120) * 32; by = (t / 120) * 32;
    } else {
        int t = blk - 4416;
        W = W_O; Wo = WOt; N = DMODEL;
        bx = (t % 24) * 32; by = (t / 24) * 32;
    }
    const int tx = tid & 31, ty = tid >> 5;
#pragma unroll
    for (int r = 0; r < 32; r += 8)
        tile[ty + r][tx] = W[(size_t)(by + ty + r) * N + bx + tx];
    __syncthreads();
#pragma unroll
    for (int r = 0; r < 32; r += 8)
        Wo[(size_t)(bx + ty + r) * DMODEL + by + tx] = f2bf(tile[tx][ty + r]);
}

// ---------------------------------------------------------------------------
// bf16 MFMA GEMM, 128x64 tile, BK=64 dual 32-wide LDS buffers, balanced
// staging. SWIZ=true: XCD-aware super-tile mapping for GEMM1
// (M=4096, N=3840 -> grid 1920, 8x10-tile super-tiles, 2.55 MB slab < 4 MiB
// per-XCD L2; assumes bid%8 -> XCD round-robin, perf-only heuristic).
// ---------------------------------------------------------------------------
template <bool BF16OUT, bool SWIZ>
__global__ __launch_bounds__(256) void gemm_bf16_n64(
    const short* __restrict__ A, const short* __restrict__ Bt,
    const float* __restrict__ bias, void* __restrict__ Cv,
    int M, int N, int K)
{
    __shared__ short As[2][128 * 32];
    __shared__ short Bs[2][64 * 32];

    const int tid  = threadIdx.x;
    const int wave = tid >> 6;
    const int lane = tid & 63;

    int bm, bn;
    if (SWIZ) {
        // 1920 blocks: xcd = bid&7; 240 per XCD = 3 super-tiles of 80
        // super-tile = 8 M-tiles x 10 N-tiles (y-fastest inside).
        int bid = blockIdx.x;
        int xcd = bid & 7, t = bid >> 3;
        int sid = (t / 80) * 8 + xcd;          // 0..23
        int inner = t % 80;
        int sy = sid / 6, sn = sid - sy * 6;   // 4 x 6 super-grid
        bm = (sy * 8 + (inner & 7)) * 128;
        bn = (sn * 10 + (inner >> 3)) * 64;
    } else {
        bm = blockIdx.y * 128;
        bn = blockIdx.x * 64;
    }

    const int st_row = lane >> 2;
    const int st_col = (lane & 3) * 8;
    const int fr_m = lane & 15;
    const int fr_k = (lane >> 4) * 8;
    const int wm = wave * 32;

    const short* gsrc[6];
    short* ldst[6];
#pragma unroll
    for (int j = 0; j < 6; ++j) {
        int c = wave * 6 + j;
        if (c < 16) {
            int kt = c >> 3, rg = c & 7;
            gsrc[j] = A + (size_t)(bm + rg * 16 + st_row) * K + kt * 32 + st_col;
            ldst[j] = &As[kt][(rg * 16) * 32];
        } else {
            int cb = c - 16;
            int kt = cb >> 2, rg = cb & 3;
            gsrc[j] = Bt + (size_t)(bn + rg * 16 + st_row) * K + kt * 32 + st_col;
            ldst[j] = &Bs[kt][(rg * 16) * 32];
        }
    }

    f32x4 acc[2][4];
#pragma unroll
    for (int mi = 0; mi < 2; ++mi)
#pragma unroll
        for (int ni = 0; ni < 4; ++ni) acc[mi][ni] = (f32x4){0.f, 0.f, 0.f, 0.f};

    for (int k0 = 0; k0 < K; k0 += 64) {
#pragma unroll
        for (int j = 0; j < 6; ++j) gload_lds16(gsrc[j] + k0, ldst[j]);
        __syncthreads();

#pragma unroll
        for (int kt = 0; kt < 2; ++kt) {
            bf16x8 af[2], bf[4];
#pragma unroll
            for (int mi = 0; mi < 2; ++mi)
                af[mi] = *reinterpret_cast<const bf16x8*>(
                    &As[kt][(wm + mi * 16 + fr_m) * 32 + fr_k]);
#pragma unroll
            for (int ni = 0; ni < 4; ++ni)
                bf[ni] = *reinterpret_cast<const bf16x8*>(
                    &Bs[kt][(ni * 16 + fr_m) * 32 + fr_k]);
#pragma unroll
            for (int mi = 0; mi < 2; ++mi)
#pragma unroll
                for (int ni = 0; ni < 4; ++ni)
                    acc[mi][ni] = __builtin_amdgcn_mfma_f32_16x16x32_bf16(
                        af[mi], bf[ni], acc[mi][ni], 0, 0, 0);
        }
        __syncthreads();
    }

    float bv[4];
#pragma unroll
    for (int ni = 0; ni < 4; ++ni)
        bv[ni] = bias[bn + ni * 16 + (lane & 15)];
#pragma unroll
    for (int mi = 0; mi < 2; ++mi) {
        int rbase = bm + wm + mi * 16 + (lane >> 4) * 4;
#pragma unroll
        for (int r = 0; r < 4; ++r) {
            size_t off = (size_t)(rbase + r) * N + bn + (lane & 15);
#pragma unroll
            for (int ni = 0; ni < 4; ++ni) {
                float val = acc[mi][ni][r] + bv[ni];
                if (BF16OUT) ((short*)Cv)[off + ni * 16] = f2bf(val);
                else         ((float*)Cv)[off + ni * 16] = val;
            }
        }
    }
}

// ---------------------------------------------------------------------------
// bf16 MFMA GEMM, 64x64 tile, BK=64 (high-TLP variant for small-N GEMM2).
// ---------------------------------------------------------------------------
__global__ __launch_bounds__(256) void gemm_bf16_64(
    const short* __restrict__ A, const short* __restrict__ Bt,
    const float* __restrict__ bias, float* __restrict__ C,
    int M, int N, int K)
{
    __shared__ short As[2][64 * 32];
    __shared__ short Bs[2][64 * 32];

    const int tid  = threadIdx.x;
    const int wave = tid >> 6;
    const int lane = tid & 63;
    const int bm = blockIdx.y * 64;
    const int bn = blockIdx.x * 64;

    const int st_row = lane >> 2;
    const int st_col = (lane & 3) * 8;
    const int fr_m = lane & 15;
    const int fr_k = (lane >> 4) * 8;
    const int wm = wave * 16;

    const short* gsrc[4];
    short* ldst[4];
#pragma unroll
    for (int j = 0; j < 4; ++j) {
        int c = wave * 4 + j;
        if (c < 8) {
            int kt = c >> 2, rg = c & 3;
            gsrc[j] = A + (size_t)(bm + rg * 16 + st_row) * K + kt * 32 + st_col;
            ldst[j] = &As[kt][(rg * 16) * 32];
        } else {
            int cb = c - 8;
            int kt = cb >> 2, rg = cb & 3;
            gsrc[j] = Bt + (size_t)(bn + rg * 16 + st_row) * K + kt * 32 + st_col;
            ldst[j] = &Bs[kt][(rg * 16) * 32];
        }
    }

    f32x4 acc[4];
#pragma unroll
    for (int ni = 0; ni < 4; ++ni) acc[ni] = (f32x4){0.f, 0.f, 0.f, 0.f};

    for (int k0 = 0; k0 < K; k0 += 64) {
#pragma unroll
        for (int j = 0; j < 4; ++j) gload_lds16(gsrc[j] + k0, ldst[j]);
        __syncthreads();

#pragma unroll
        for (int kt = 0; kt < 2; ++kt) {
            bf16x8 af = *reinterpret_cast<const bf16x8*>(
                &As[kt][(wm + fr_m) * 32 + fr_k]);
#pragma unroll
            for (int ni = 0; ni < 4; ++ni) {
                bf16x8 bf = *reinterpret_cast<const bf16x8*>(
                    &Bs[kt][(ni * 16 + fr_m) * 32 + fr_k]);
                acc[ni] = __builtin_amdgcn_mfma_f32_16x16x32_bf16(
                    af, bf, acc[ni], 0, 0, 0);
            }
        }
        __syncthreads();
    }

    float bv[4];
#pragma unroll
    for (int ni = 0; ni < 4; ++ni)
        bv[ni] = bias[bn + ni * 16 + (lane & 15)];
    int rbase = bm + wm + (lane >> 4) * 4;
#pragma unroll
    for (int r = 0; r < 4; ++r) {
        size_t off = (size_t)(rbase + r) * N + bn + (lane & 15);
#pragma unroll
        for (int ni = 0; ni < 4; ++ni)
            C[off + ni * 16] = acc[ni][r] + bv[ni];
    }
}

// ---------------------------------------------------------------------------
// Windowed trittention, wave-private softmax + pair-tree pm reduction.
// (unchanged from round 9: VGPR 84, no launch-bounds cap — a cap spills)
// ---------------------------------------------------------------------------
__global__ __launch_bounds__(256) void attn_kernel(
    const short* __restrict__ abcde, short* __restrict__ z)
{
    const int blk = blockIdx.x;
    const int n  = blk & (NWIN - 1);
    const int bh = blk >> 7;
    const int b  = bh / NHEADS;
    const int h  = bh % NHEADS;

    __shared__ short sc[WIN * PAD_K];
    __shared__ short sa[WW * PAD_K];
    __shared__ short sb[WW * PAD_K];
    __shared__ short sd[WW * PAD_K];
    __shared__ short se[WW * PAD_K];
    __shared__ short epA[WIN * PAD_K];     // [i][0..31]=pm, [32..63]=pl (bf16, unnorm)
    __shared__ float sinv[WIN];

    const int tid = threadIdx.x;
    const size_t rowbase = ((size_t)b * T_SEQ) * NABCDE;
    const int hd = h * DHEAD;

    // ---- staging
    if (tid < 128) {
        int row = tid >> 3, ch = (tid & 7) * 8;
        *reinterpret_cast<uint4*>(&sc[row * PAD_K + ch]) =
            *reinterpret_cast<const uint4*>(
                &abcde[rowbase + (size_t)(n * WIN + row) * NABCDE + 2 * DMODEL + hd + ch]);
    }
    {
        int row = tid >> 3, ch = (tid & 7) * 8;
        int t = n * WIN - WIN + row;
        uint4 va = {0u, 0u, 0u, 0u}, vb = va, vd = va, ve = va;
        if (t >= 0) {
            size_t base = rowbase + (size_t)t * NABCDE + hd + ch;
            va = *reinterpret_cast<const uint4*>(&abcde[base + 0 * DMODEL]);
            vb = *reinterpret_cast<const uint4*>(&abcde[base + 1 * DMODEL]);
            vd = *reinterpret_cast<const uint4*>(&abcde[base + 3 * DMODEL]);
            ve = *reinterpret_cast<const uint4*>(&abcde[base + 4 * DMODEL]);
        }
        *reinterpret_cast<uint4*>(&sa[row * PAD_K + ch]) = va;
        *reinterpret_cast<uint4*>(&sb[row * PAD_K + ch]) = vb;
        *reinterpret_cast<uint4*>(&sd[row * PAD_K + ch]) = vd;
        *reinterpret_cast<uint4*>(&se[row * PAD_K + ch]) = ve;
    }
    __syncthreads();   // B1

    const int wv = tid >> 6;
    const int lane = tid & 63;
    const int lc = lane & 15;
    const int ko = lane >> 4;

    // ---- c fragment pre-split into (lo,hi) float2 pairs; b fragments raw
    f32x2 c2[2][4];
    bf16x8 bfrag[2][2];
#pragma unroll
    for (int kt = 0; kt < 2; ++kt) {
        union { bf16x8 v; unsigned u[4]; } Cf;
        Cf.v = *reinterpret_cast<const bf16x8*>(
            &sc[(wv * 4 + (lc & 3)) * PAD_K + kt * 32 + ko * 8]);
#pragma unroll
        for (int j = 0; j < 4; ++j) {
            c2[kt][j] = (f32x2){__uint_as_float(Cf.u[j] << 16),
                                __uint_as_float(Cf.u[j] & 0xffff0000u)};
        }
        bfrag[0][kt] = *reinterpret_cast<const bf16x8*>(&sb[lc * PAD_K + kt * 32 + ko * 8]);
        bfrag[1][kt] = *reinterpret_cast<const bf16x8*>(&sb[(16 + lc) * PAD_K + kt * 32 + ko * 8]);
    }

    f32x4 acc[8][2];
#pragma unroll
    for (int mt = 0; mt < 8; ++mt) {
        acc[mt][0] = (f32x4){0.f, 0.f, 0.f, 0.f};
        acc[mt][1] = (f32x4){0.f, 0.f, 0.f, 0.f};
    }
#pragma unroll
    for (int mt = 0; mt < 8; ++mt) {
#pragma unroll
        for (int kt = 0; kt < 2; ++kt) {
            union { bf16x8 v; unsigned u[4]; } Ar, Rf;
            Ar.v = *reinterpret_cast<const bf16x8*>(
                &sa[(mt * 4 + (lc >> 2)) * PAD_K + kt * 32 + ko * 8]);
#pragma unroll
            for (int j = 0; j < 4; ++j) {
                f32x2 y = (f32x2){__uint_as_float(Ar.u[j] << 16),
                                  __uint_as_float(Ar.u[j] & 0xffff0000u)};
                f32x2 p = c2[kt][j] * y;          // -> v_pk_mul_f32
                Rf.u[j] = __builtin_amdgcn_perm(
                    __float_as_uint(p[1]), __float_as_uint(p[0]), 0x07060302);
            }
            acc[mt][0] = __builtin_amdgcn_mfma_f32_16x16x32_bf16(Rf.v, bfrag[0][kt], acc[mt][0], 0, 0, 0);
            acc[mt][1] = __builtin_amdgcn_mfma_f32_16x16x32_bf16(Rf.v, bfrag[1][kt], acc[mt][1], 0, 0, 0);
        }
    }

    // ---- mask: keepL hoisted; zero-hack only for padded window n==0
    const int nbase = n * WIN;
    int bbl_h[2];
    bool keepL[2][4];
#pragma unroll
    for (int lt = 0; lt < 2; ++lt) {
        int l = lt * 16 + lc;
        bbl_h[lt] = (n == 0 && l < WIN) ? 0 : (nbase - WIN + l);
#pragma unroll
        for (int reg = 0; reg < 4; ++reg)
            keepL[lt][reg] = (nbase + wv * 4 + reg) >= bbl_h[lt];
    }
#pragma unroll
    for (int mt = 0; mt < 8; ++mt) {
        int m = mt * 4 + ko;
        int bbm = (n == 0 && m < WIN) ? 0 : (nbase - WIN + m);
#pragma unroll
        for (int lt = 0; lt < 2; ++lt) {
            bool mgt = bbl_h[lt] > bbm;
#pragma unroll
            for (int reg = 0; reg < 4; ++reg) {
                if (!(keepL[lt][reg] && mgt)) acc[mt][lt][reg] = IGNORE_V;
            }
        }
    }
    if (n == 0) {
#pragma unroll
        for (int mt = 0; mt < 8; ++mt)
#pragma unroll
            for (int lt = 0; lt < 2; ++lt)
#pragma unroll
                for (int reg = 0; reg < 4; ++reg)
                    if (acc[mt][lt][reg] == 0.0f) acc[mt][lt][reg] = IGNORE_V;
    }

    // ---- per-query max
    float mx[4] = {-3.4e38f, -3.4e38f, -3.4e38f, -3.4e38f};
#pragma unroll
    for (int mt = 0; mt < 8; ++mt)
#pragma unroll
        for (int lt = 0; lt < 2; ++lt)
#pragma unroll
            for (int reg = 0; reg < 4; ++reg)
                mx[reg] = fmaxf(mx[reg], acc[mt][lt][reg]);
#pragma unroll
    for (int reg = 0; reg < 4; ++reg) {
#pragma unroll
        for (int off = 1; off < 64; off <<= 1)
            mx[reg] = fmaxf(mx[reg], __shfl_xor(mx[reg], off, 64));
    }

    // ---- exp2-folded softmax numerator
    float c0[4];
#pragma unroll
    for (int reg = 0; reg < 4; ++reg) c0[reg] = -mx[reg] * L2E64;
#pragma unroll
    for (int mt = 0; mt < 8; ++mt)
#pragma unroll
        for (int lt = 0; lt < 2; ++lt)
#pragma unroll
            for (int reg = 0; reg < 4; ++reg)
                acc[mt][lt][reg] = exp2f(fmaf(acc[mt][lt][reg], L2E64, c0[reg]));

    // ---- pl (col-marginal over m) + epA cols 32..63; keep plv for sm
    float plv[2][4];
#pragma unroll
    for (int lt = 0; lt < 2; ++lt) {
#pragma unroll
        for (int reg = 0; reg < 4; ++reg) {
            float p = acc[0][lt][reg];
#pragma unroll
            for (int mt = 1; mt < 8; ++mt) p += acc[mt][lt][reg];
            p += __shfl_xor(p, 16, 64);
            p += __shfl_xor(p, 32, 64);
            plv[lt][reg] = p;
        }
        float w  = (ko & 1) ? plv[lt][1] : plv[lt][0];
        float w2 = (ko & 1) ? plv[lt][3] : plv[lt][2];
        float ww = (ko & 2) ? w2 : w;
        epA[(wv * 4 + ko) * PAD_K + 32 + lt * 16 + lc] = f2bf(ww);
    }

    // ---- sm[i] = sum_l pl[i][l]
    {
        float s[4];
#pragma unroll
        for (int reg = 0; reg < 4; ++reg) {
            float t = plv[0][reg] + plv[1][reg];
            t += __shfl_xor(t, 1, 64);
            t += __shfl_xor(t, 2, 64);
            t += __shfl_xor(t, 4, 64);
            t += __shfl_xor(t, 8, 64);
            s[reg] = t;
        }
        if (lane == 0) {
#pragma unroll
            for (int reg = 0; reg < 4; ++reg) sinv[wv * 4 + reg] = 1.0f / s[reg];
        }
    }

    // ---- pm via pair-tree over lc; write epA cols 0..31
    {
        float v8[8][4];
#pragma unroll
        for (int mt = 0; mt < 8; ++mt)
#pragma unroll
            for (int reg = 0; reg < 4; ++reg)
                v8[mt][reg] = acc[mt][0][reg] + acc[mt][1][reg];

        const bool s0 = lane & 1, s1 = lane & 2, s2 = lane & 4, s3 = lane & 8;
        float r1[4][4];
#pragma unroll
        for (int m2 = 0; m2 < 4; ++m2)
#pragma unroll
            for (int reg = 0; reg < 4; ++reg) {
                float u = v8[2 * m2][reg], w = v8[2 * m2 + 1][reg];
                float a = s0 ? w : u;
                float s = s0 ? u : w;
                r1[m2][reg] = a + __shfl_xor(s, 1, 64);
            }
        float r2[2][4];
#pragma unroll
        for (int m4 = 0; m4 < 2; ++m4)
#pragma unroll
            for (int reg = 0; reg < 4; ++reg) {
                float u = r1[2 * m4][reg], w = r1[2 * m4 + 1][reg];
                float a = s1 ? w : u;
                float s = s1 ? u : w;
                r2[m4][reg] = a + __shfl_xor(s, 2, 64);
            }
        float r3[4];
#pragma unroll
        for (int reg = 0; reg < 4; ++reg) {
            float u = r2[0][reg], w = r2[1][reg];
            float a = s2 ? w : u;
            float s = s2 ? u : w;
            r3[reg] = a + __shfl_xor(s, 4, 64);
        }
        float a0 = s3 ? r3[1] : r3[0];
        float q0 = s3 ? r3[0] : r3[1];
        float g0 = a0 + __shfl_xor(q0, 8, 64);
        float a1 = s3 ? r3[3] : r3[2];
        float q1 = s3 ? r3[2] : r3[3];
        float g1 = a1 + __shfl_xor(q1, 8, 64);

        int mcol = (lc & 7) * 4 + ko;
        int ib = wv * 4 + (lc >> 3);
        epA[ib * PAD_K + mcol]       = f2bf(g0);
        epA[(ib + 2) * PAD_K + mcol] = f2bf(g1);
    }

    // ---- epilogue B-frags from sd/se (pre-barrier; dd = wv*16+lc)
    const int dd = wv * 16 + lc;
    bf16x8 bd, be;
    {
        unsigned dv[8], ev[8];
#pragma unroll
        for (int j = 0; j < 8; ++j) {
            dv[j] = *reinterpret_cast<const unsigned short*>(&sd[(ko * 8 + j) * PAD_K + dd]);
            ev[j] = *reinterpret_cast<const unsigned short*>(&se[(ko * 8 + j) * PAD_K + dd]);
        }
        union { unsigned u[4]; bf16x8 v; } td, te;
#pragma unroll
        for (int j = 0; j < 4; ++j) {
            td.u[j] = __builtin_amdgcn_perm(dv[2 * j + 1], dv[2 * j], 0x05040100);
            te.u[j] = __builtin_amdgcn_perm(ev[2 * j + 1], ev[2 * j], 0x05040100);
        }
        bd = td.v; be = te.v;
    }
    __syncthreads();   // B2

    // ---- cooperative epilogue MFMA
    bf16x8 apm = *reinterpret_cast<const bf16x8*>(&epA[lc * PAD_K + ko * 8]);
    bf16x8 apl = *reinterpret_cast<const bf16x8*>(&epA[lc * PAD_K + 32 + ko * 8]);
    f32x4 zacc = (f32x4){0.f, 0.f, 0.f, 0.f};
    zacc = __builtin_amdgcn_mfma_f32_16x16x32_bf16(apm, bd, zacc, 0, 0, 0);
    zacc = __builtin_amdgcn_mfma_f32_16x16x32_bf16(apl, be, zacc, 0, 0, 0);

#pragma unroll
    for (int reg = 0; reg < 4; ++reg) {
        int i = ko * 4 + reg;
        z[((size_t)b * T_SEQ + nbase + i) * (NHEADS * DHEAD) + hd + dd] =
            f2bf(zacc[reg] * sinv[i]);
    }
}

// ---------------------------------------------------------------------------
extern "C" void kernel_launch(void* const* d_in, const int* in_sizes, int n_in,
                              void* d_out, int out_size, void* d_ws, size_t ws_size,
                              hipStream_t stream) {
    const float* x        = (const float*)d_in[0];
    const float* W_abcde  = (const float*)d_in[1];
    const float* b_abcde  = (const float*)d_in[2];
    const float* W_O      = (const float*)d_in[3];
    const float* b_O      = (const float*)d_in[4];
    float* out = (float*)d_out;

    char* ws = (char*)d_ws;
    short* abcde = (short*)ws;                                  // 4096x3840 bf16 (31.5 MB)
    short* xb    = (short*)(ws + (size_t)31457280);             // 4096x768 bf16, reused as zb
    short* Wt    = (short*)(ws + (size_t)31457280 + 6291456);   // 3840x768 bf16
    short* WOt   = (short*)(ws + (size_t)31457280 + 6291456 + 5898240); // 768x768 bf16
    short* zb    = xb;

    const int M = 2 * T_SEQ;  // 4096

    prep_kernel<<<dim3(4992), dim3(256), 0, stream>>>(
        x, W_abcde, W_O, xb, Wt, WOt);

    // GEMM1 with XCD super-tile swizzle (1D grid of 1920)
    gemm_bf16_n64<true, true><<<dim3(1920), dim3(256), 0, stream>>>(
        xb, Wt, b_abcde, (void*)abcde, M, NABCDE, DMODEL);

    attn_kernel<<<dim3(2 * NHEADS * NWIN), dim3(256), 0, stream>>>(abcde, zb);

    gemm_bf16_64<<<dim3(DMODEL / 64, M / 64), dim3(256), 0, stream>>>(
        zb, WOt, b_O, out, M, DMODEL, DMODEL);
}

// Round 11
// 167.059 us; speedup vs baseline: 1.1729x; 1.0106x over previous
//
#include <hip/hip_runtime.h>

#define T_SEQ   2048
#define NHEADS  12
#define DHEAD   64
#define WIN     16
#define WW      32
#define NWIN    128
#define DMODEL  768
#define NABCDE  3840
#define IGNORE_V (-1.0e6f)
#define PAD_K   72          // bf16 LDS row stride (144 B, 16B-aligned)
#define L2E64   0.022542110013890053f   // log2(e)/64

typedef float f32x4 __attribute__((ext_vector_type(4)));
typedef float f32x2 __attribute__((ext_vector_type(2)));
typedef short bf16x8 __attribute__((ext_vector_type(8)));

__device__ __forceinline__ short f2bf(float f) {
    unsigned u = __float_as_uint(f);
    unsigned r = (u + 0x7FFF + ((u >> 16) & 1)) >> 16;   // RNE
    return (short)r;
}

__device__ __forceinline__ void gload_lds16(const short* g, short* l) {
    __builtin_amdgcn_global_load_lds(
        (const __attribute__((address_space(1))) void*)g,
        (__attribute__((address_space(3))) void*)l,
        16, 0, 0);
}

// ---------------------------------------------------------------------------
// merged prep: [0,1536) cast x -> xb; [1536,4416) transpose W_abcde -> Wt;
// [4416,4992) transpose W_O -> WOt.
// ---------------------------------------------------------------------------
__global__ __launch_bounds__(256) void prep_kernel(
    const float* __restrict__ x, const float* __restrict__ W_abcde,
    const float* __restrict__ W_O,
    short* __restrict__ xb, short* __restrict__ Wt, short* __restrict__ WOt)
{
    __shared__ float tile[32][33];
    const int blk = blockIdx.x;
    const int tid = threadIdx.x;

    if (blk < 1536) {
        int i = (blk * 256 + tid) * 8;
        float4 a = *reinterpret_cast<const float4*>(&x[i]);
        float4 b = *reinterpret_cast<const float4*>(&x[i + 4]);
        union { short s[8]; uint4 u; } r;
        r.s[0] = f2bf(a.x); r.s[1] = f2bf(a.y); r.s[2] = f2bf(a.z); r.s[3] = f2bf(a.w);
        r.s[4] = f2bf(b.x); r.s[5] = f2bf(b.y); r.s[6] = f2bf(b.z); r.s[7] = f2bf(b.w);
        *reinterpret_cast<uint4*>(&xb[i]) = r.u;
        return;
    }
    const float* W; short* Wo; int N, bx, by;
    if (blk < 4416) {
        int t = blk - 1536;
        W = W_abcde; Wo = Wt; N = NABCDE;
        bx = (t % 120) * 32; by = (t / 120) * 32;
    } else {
        int t = blk - 4416;
        W = W_O; Wo = WOt; N = DMODEL;
        bx = (t % 24) * 32; by = (t / 24) * 32;
    }
    const int tx = tid & 31, ty = tid >> 5;
#pragma unroll
    for (int r = 0; r < 32; r += 8)
        tile[ty + r][tx] = W[(size_t)(by + ty + r) * N + bx + tx];
    __syncthreads();
#pragma unroll
    for (int r = 0; r < 32; r += 8)
        Wo[(size_t)(bx + ty + r) * DMODEL + by + tx] = f2bf(tile[tx][ty + r]);
}

// ---------------------------------------------------------------------------
// GEMM1: bf16 MFMA, 128x64 tile, BK=64, balanced staging, XCD super-tile
// swizzle, bf16 output COALESCED via LDS repack (fixes 4x write-amp from
// 2B scalar stores).
// ---------------------------------------------------------------------------
__global__ __launch_bounds__(256) void gemm1_kernel(
    const short* __restrict__ A, const short* __restrict__ Bt,
    const float* __restrict__ bias, short* __restrict__ C,
    int M, int N, int K)
{
    __shared__ short As[2][128 * 32];
    __shared__ short Bs[2][64 * 32];

    const int tid  = threadIdx.x;
    const int wave = tid >> 6;
    const int lane = tid & 63;

    // 1920 blocks: xcd = bid&7; 240 per XCD = 3 super-tiles of 80
    int bid = blockIdx.x;
    int xcd = bid & 7, t = bid >> 3;
    int sid = (t / 80) * 8 + xcd;
    int inner = t % 80;
    int sy = sid / 6, sn = sid - sy * 6;
    const int bm = (sy * 8 + (inner & 7)) * 128;
    const int bn = (sn * 10 + (inner >> 3)) * 64;

    const int st_row = lane >> 2;
    const int st_col = (lane & 3) * 8;
    const int fr_m = lane & 15;
    const int fr_k = (lane >> 4) * 8;
    const int wm = wave * 32;
    const int lc = lane & 15;
    const int ko = lane >> 4;

    const short* gsrc[6];
    short* ldst[6];
#pragma unroll
    for (int j = 0; j < 6; ++j) {
        int c = wave * 6 + j;
        if (c < 16) {
            int kt = c >> 3, rg = c & 7;
            gsrc[j] = A + (size_t)(bm + rg * 16 + st_row) * K + kt * 32 + st_col;
            ldst[j] = &As[kt][(rg * 16) * 32];
        } else {
            int cb = c - 16;
            int kt = cb >> 2, rg = cb & 3;
            gsrc[j] = Bt + (size_t)(bn + rg * 16 + st_row) * K + kt * 32 + st_col;
            ldst[j] = &Bs[kt][(rg * 16) * 32];
        }
    }

    f32x4 acc[2][4];
#pragma unroll
    for (int mi = 0; mi < 2; ++mi)
#pragma unroll
        for (int ni = 0; ni < 4; ++ni) acc[mi][ni] = (f32x4){0.f, 0.f, 0.f, 0.f};

    for (int k0 = 0; k0 < K; k0 += 64) {
#pragma unroll
        for (int j = 0; j < 6; ++j) gload_lds16(gsrc[j] + k0, ldst[j]);
        __syncthreads();

#pragma unroll
        for (int kt = 0; kt < 2; ++kt) {
            bf16x8 af[2], bf[4];
#pragma unroll
            for (int mi = 0; mi < 2; ++mi)
                af[mi] = *reinterpret_cast<const bf16x8*>(
                    &As[kt][(wm + mi * 16 + fr_m) * 32 + fr_k]);
#pragma unroll
            for (int ni = 0; ni < 4; ++ni)
                bf[ni] = *reinterpret_cast<const bf16x8*>(
                    &Bs[kt][(ni * 16 + fr_m) * 32 + fr_k]);
#pragma unroll
            for (int mi = 0; mi < 2; ++mi)
#pragma unroll
                for (int ni = 0; ni < 4; ++ni)
                    acc[mi][ni] = __builtin_amdgcn_mfma_f32_16x16x32_bf16(
                        af[mi], bf[ni], acc[mi][ni], 0, 0, 0);
        }
        __syncthreads();
    }

    // epilogue: pack bf16 C tile (128x64) into LDS, then coalesced stores
    float bv[4];
#pragma unroll
    for (int ni = 0; ni < 4; ++ni)
        bv[ni] = bias[bn + ni * 16 + lc];

    short* cb = &As[0][0];                      // 8192 shorts, free after loop
#pragma unroll
    for (int mi = 0; mi < 2; ++mi) {
#pragma unroll
        for (int r = 0; r < 4; ++r) {
            int row = wm + mi * 16 + ko * 4 + r;
#pragma unroll
            for (int ni = 0; ni < 4; ++ni)
                cb[row * 64 + ni * 16 + lc] = f2bf(acc[mi][ni][r] + bv[ni]);
        }
    }
    __syncthreads();
    // 128 rows x 64 shorts (128B); 1024 uint4 chunks, 4 per thread
#pragma unroll
    for (int q = 0; q < 4; ++q) {
        int f = tid + q * 256;
        int row = f >> 3, c16 = (f & 7) * 8;
        *reinterpret_cast<uint4*>(&C[(size_t)(bm + row) * N + bn + c16]) =
            *reinterpret_cast<const uint4*>(&cb[row * 64 + c16]);
    }
}

// ---------------------------------------------------------------------------
// GEMM2: bf16 MFMA, 64x64 tile, BK=64 (high-TLP), fp32 out.
// ---------------------------------------------------------------------------
__global__ __launch_bounds__(256) void gemm_bf16_64(
    const short* __restrict__ A, const short* __restrict__ Bt,
    const float* __restrict__ bias, float* __restrict__ C,
    int M, int N, int K)
{
    __shared__ short As[2][64 * 32];
    __shared__ short Bs[2][64 * 32];

    const int tid  = threadIdx.x;
    const int wave = tid >> 6;
    const int lane = tid & 63;
    const int bm = blockIdx.y * 64;
    const int bn = blockIdx.x * 64;

    const int st_row = lane >> 2;
    const int st_col = (lane & 3) * 8;
    const int fr_m = lane & 15;
    const int fr_k = (lane >> 4) * 8;
    const int wm = wave * 16;

    const short* gsrc[4];
    short* ldst[4];
#pragma unroll
    for (int j = 0; j < 4; ++j) {
        int c = wave * 4 + j;
        if (c < 8) {
            int kt = c >> 2, rg = c & 3;
            gsrc[j] = A + (size_t)(bm + rg * 16 + st_row) * K + kt * 32 + st_col;
            ldst[j] = &As[kt][(rg * 16) * 32];
        } else {
            int cb = c - 8;
            int kt = cb >> 2, rg = cb & 3;
            gsrc[j] = Bt + (size_t)(bn + rg * 16 + st_row) * K + kt * 32 + st_col;
            ldst[j] = &Bs[kt][(rg * 16) * 32];
        }
    }

    f32x4 acc[4];
#pragma unroll
    for (int ni = 0; ni < 4; ++ni) acc[ni] = (f32x4){0.f, 0.f, 0.f, 0.f};

    for (int k0 = 0; k0 < K; k0 += 64) {
#pragma unroll
        for (int j = 0; j < 4; ++j) gload_lds16(gsrc[j] + k0, ldst[j]);
        __syncthreads();

#pragma unroll
        for (int kt = 0; kt < 2; ++kt) {
            bf16x8 af = *reinterpret_cast<const bf16x8*>(
                &As[kt][(wm + fr_m) * 32 + fr_k]);
#pragma unroll
            for (int ni = 0; ni < 4; ++ni) {
                bf16x8 bf = *reinterpret_cast<const bf16x8*>(
                    &Bs[kt][(ni * 16 + fr_m) * 32 + fr_k]);
                acc[ni] = __builtin_amdgcn_mfma_f32_16x16x32_bf16(
                    af, bf, acc[ni], 0, 0, 0);
            }
        }
        __syncthreads();
    }

    float bv[4];
#pragma unroll
    for (int ni = 0; ni < 4; ++ni)
        bv[ni] = bias[bn + ni * 16 + (lane & 15)];
    int rbase = bm + wm + (lane >> 4) * 4;
#pragma unroll
    for (int r = 0; r < 4; ++r) {
        size_t off = (size_t)(rbase + r) * N + bn + (lane & 15);
#pragma unroll
        for (int ni = 0; ni < 4; ++ni)
            C[off + ni * 16] = acc[ni][r] + bv[ni];
    }
}

// ---------------------------------------------------------------------------
// Windowed trittention, wave-private softmax + pair-tree pm reduction.
// z-store now COALESCED via LDS repack (fixes 4x write-amp).
// ---------------------------------------------------------------------------
__global__ __launch_bounds__(256) void attn_kernel(
    const short* __restrict__ abcde, short* __restrict__ z)
{
    const int blk = blockIdx.x;
    const int n  = blk & (NWIN - 1);
    const int bh = blk >> 7;
    const int b  = bh / NHEADS;
    const int h  = bh % NHEADS;

    __shared__ short sc[WIN * PAD_K];
    __shared__ short sa[WW * PAD_K];
    __shared__ short sb[WW * PAD_K];
    __shared__ short sd[WW * PAD_K];
    __shared__ short se[WW * PAD_K];
    __shared__ short epA[WIN * PAD_K];     // [i][0..31]=pm, [32..63]=pl (bf16, unnorm)
    __shared__ float sinv[WIN];

    const int tid = threadIdx.x;
    const size_t rowbase = ((size_t)b * T_SEQ) * NABCDE;
    const int hd = h * DHEAD;

    // ---- staging
    if (tid < 128) {
        int row = tid >> 3, ch = (tid & 7) * 8;
        *reinterpret_cast<uint4*>(&sc[row * PAD_K + ch]) =
            *reinterpret_cast<const uint4*>(
                &abcde[rowbase + (size_t)(n * WIN + row) * NABCDE + 2 * DMODEL + hd + ch]);
    }
    {
        int row = tid >> 3, ch = (tid & 7) * 8;
        int t = n * WIN - WIN + row;
        uint4 va = {0u, 0u, 0u, 0u}, vb = va, vd = va, ve = va;
        if (t >= 0) {
            size_t base = rowbase + (size_t)t * NABCDE + hd + ch;
            va = *reinterpret_cast<const uint4*>(&abcde[base + 0 * DMODEL]);
            vb = *reinterpret_cast<const uint4*>(&abcde[base + 1 * DMODEL]);
            vd = *reinterpret_cast<const uint4*>(&abcde[base + 3 * DMODEL]);
            ve = *reinterpret_cast<const uint4*>(&abcde[base + 4 * DMODEL]);
        }
        *reinterpret_cast<uint4*>(&sa[row * PAD_K + ch]) = va;
        *reinterpret_cast<uint4*>(&sb[row * PAD_K + ch]) = vb;
        *reinterpret_cast<uint4*>(&sd[row * PAD_K + ch]) = vd;
        *reinterpret_cast<uint4*>(&se[row * PAD_K + ch]) = ve;
    }
    __syncthreads();   // B1

    const int wv = tid >> 6;
    const int lane = tid & 63;
    const int lc = lane & 15;
    const int ko = lane >> 4;

    // ---- c fragment pre-split into (lo,hi) float2 pairs; b fragments raw
    f32x2 c2[2][4];
    bf16x8 bfrag[2][2];
#pragma unroll
    for (int kt = 0; kt < 2; ++kt) {
        union { bf16x8 v; unsigned u[4]; } Cf;
        Cf.v = *reinterpret_cast<const bf16x8*>(
            &sc[(wv * 4 + (lc & 3)) * PAD_K + kt * 32 + ko * 8]);
#pragma unroll
        for (int j = 0; j < 4; ++j) {
            c2[kt][j] = (f32x2){__uint_as_float(Cf.u[j] << 16),
                                __uint_as_float(Cf.u[j] & 0xffff0000u)};
        }
        bfrag[0][kt] = *reinterpret_cast<const bf16x8*>(&sb[lc * PAD_K + kt * 32 + ko * 8]);
        bfrag[1][kt] = *reinterpret_cast<const bf16x8*>(&sb[(16 + lc) * PAD_K + kt * 32 + ko * 8]);
    }

    f32x4 acc[8][2];
#pragma unroll
    for (int mt = 0; mt < 8; ++mt) {
        acc[mt][0] = (f32x4){0.f, 0.f, 0.f, 0.f};
        acc[mt][1] = (f32x4){0.f, 0.f, 0.f, 0.f};
    }
#pragma unroll
    for (int mt = 0; mt < 8; ++mt) {
#pragma unroll
        for (int kt = 0; kt < 2; ++kt) {
            union { bf16x8 v; unsigned u[4]; } Ar, Rf;
            Ar.v = *reinterpret_cast<const bf16x8*>(
                &sa[(mt * 4 + (lc >> 2)) * PAD_K + kt * 32 + ko * 8]);
#pragma unroll
            for (int j = 0; j < 4; ++j) {
                f32x2 y = (f32x2){__uint_as_float(Ar.u[j] << 16),
                                  __uint_as_float(Ar.u[j] & 0xffff0000u)};
                f32x2 p = c2[kt][j] * y;          // -> v_pk_mul_f32
                Rf.u[j] = __builtin_amdgcn_perm(
                    __float_as_uint(p[1]), __float_as_uint(p[0]), 0x07060302);
            }
            acc[mt][0] = __builtin_amdgcn_mfma_f32_16x16x32_bf16(Rf.v, bfrag[0][kt], acc[mt][0], 0, 0, 0);
            acc[mt][1] = __builtin_amdgcn_mfma_f32_16x16x32_bf16(Rf.v, bfrag[1][kt], acc[mt][1], 0, 0, 0);
        }
    }

    // ---- mask: keepL hoisted; zero-hack only for padded window n==0
    const int nbase = n * WIN;
    int bbl_h[2];
    bool keepL[2][4];
#pragma unroll
    for (int lt = 0; lt < 2; ++lt) {
        int l = lt * 16 + lc;
        bbl_h[lt] = (n == 0 && l < WIN) ? 0 : (nbase - WIN + l);
#pragma unroll
        for (int reg = 0; reg < 4; ++reg)
            keepL[lt][reg] = (nbase + wv * 4 + reg) >= bbl_h[lt];
    }
#pragma unroll
    for (int mt = 0; mt < 8; ++mt) {
        int m = mt * 4 + ko;
        int bbm = (n == 0 && m < WIN) ? 0 : (nbase - WIN + m);
#pragma unroll
        for (int lt = 0; lt < 2; ++lt) {
            bool mgt = bbl_h[lt] > bbm;
#pragma unroll
            for (int reg = 0; reg < 4; ++reg) {
                if (!(keepL[lt][reg] && mgt)) acc[mt][lt][reg] = IGNORE_V;
            }
        }
    }
    if (n == 0) {
#pragma unroll
        for (int mt = 0; mt < 8; ++mt)
#pragma unroll
            for (int lt = 0; lt < 2; ++lt)
#pragma unroll
                for (int reg = 0; reg < 4; ++reg)
                    if (acc[mt][lt][reg] == 0.0f) acc[mt][lt][reg] = IGNORE_V;
    }

    // ---- per-query max
    float mx[4] = {-3.4e38f, -3.4e38f, -3.4e38f, -3.4e38f};
#pragma unroll
    for (int mt = 0; mt < 8; ++mt)
#pragma unroll
        for (int lt = 0; lt < 2; ++lt)
#pragma unroll
            for (int reg = 0; reg < 4; ++reg)
                mx[reg] = fmaxf(mx[reg], acc[mt][lt][reg]);
#pragma unroll
    for (int reg = 0; reg < 4; ++reg) {
#pragma unroll
        for (int off = 1; off < 64; off <<= 1)
            mx[reg] = fmaxf(mx[reg], __shfl_xor(mx[reg], off, 64));
    }

    // ---- exp2-folded softmax numerator
    float c0[4];
#pragma unroll
    for (int reg = 0; reg < 4; ++reg) c0[reg] = -mx[reg] * L2E64;
#pragma unroll
    for (int mt = 0; mt < 8; ++mt)
#pragma unroll
        for (int lt = 0; lt < 2; ++lt)
#pragma unroll
            for (int reg = 0; reg < 4; ++reg)
                acc[mt][lt][reg] = exp2f(fmaf(acc[mt][lt][reg], L2E64, c0[reg]));

    // ---- pl (col-marginal over m) + epA cols 32..63; keep plv for sm
    float plv[2][4];
#pragma unroll
    for (int lt = 0; lt < 2; ++lt) {
#pragma unroll
        for (int reg = 0; reg < 4; ++reg) {
            float p = acc[0][lt][reg];
#pragma unroll
            for (int mt = 1; mt < 8; ++mt) p += acc[mt][lt][reg];
            p += __shfl_xor(p, 16, 64);
            p += __shfl_xor(p, 32, 64);
            plv[lt][reg] = p;
        }
        float w  = (ko & 1) ? plv[lt][1] : plv[lt][0];
        float w2 = (ko & 1) ? plv[lt][3] : plv[lt][2];
        float ww = (ko & 2) ? w2 : w;
        epA[(wv * 4 + ko) * PAD_K + 32 + lt * 16 + lc] = f2bf(ww);
    }

    // ---- sm[i] = sum_l pl[i][l]
    {
        float s[4];
#pragma unroll
        for (int reg = 0; reg < 4; ++reg) {
            float t = plv[0][reg] + plv[1][reg];
            t += __shfl_xor(t, 1, 64);
            t += __shfl_xor(t, 2, 64);
            t += __shfl_xor(t, 4, 64);
            t += __shfl_xor(t, 8, 64);
            s[reg] = t;
        }
        if (lane == 0) {
#pragma unroll
            for (int reg = 0; reg < 4; ++reg) sinv[wv * 4 + reg] = 1.0f / s[reg];
        }
    }

    // ---- pm via pair-tree over lc; write epA cols 0..31
    {
        float v8[8][4];
#pragma unroll
        for (int mt = 0; mt < 8; ++mt)
#pragma unroll
            for (int reg = 0; reg < 4; ++reg)
                v8[mt][reg] = acc[mt][0][reg] + acc[mt][1][reg];

        const bool s0 = lane & 1, s1 = lane & 2, s2 = lane & 4, s3 = lane & 8;
        float r1[4][4];
#pragma unroll
        for (int m2 = 0; m2 < 4; ++m2)
#pragma unroll
            for (int reg = 0; reg < 4; ++reg) {
                float u = v8[2 * m2][reg], w = v8[2 * m2 + 1][reg];
                float a = s0 ? w : u;
                float s = s0 ? u : w;
                r1[m2][reg] = a + __shfl_xor(s, 1, 64);
            }
        float r2[2][4];
#pragma unroll
        for (int m4 = 0; m4 < 2; ++m4)
#pragma unroll
            for (int reg = 0; reg < 4; ++reg) {
                float u = r1[2 * m4][reg], w = r1[2 * m4 + 1][reg];
                float a = s1 ? w : u;
                float s = s1 ? u : w;
                r2[m4][reg] = a + __shfl_xor(s, 2, 64);
            }
        float r3[4];
#pragma unroll
        for (int reg = 0; reg < 4; ++reg) {
            float u = r2[0][reg], w = r2[1][reg];
            float a = s2 ? w : u;
            float s = s2 ? u : w;
            r3[reg] = a + __shfl_xor(s, 4, 64);
        }
        float a0 = s3 ? r3[1] : r3[0];
        float q0 = s3 ? r3[0] : r3[1];
        float g0 = a0 + __shfl_xor(q0, 8, 64);
        float a1 = s3 ? r3[3] : r3[2];
        float q1 = s3 ? r3[2] : r3[3];
        float g1 = a1 + __shfl_xor(q1, 8, 64);

        int mcol = (lc & 7) * 4 + ko;
        int ib = wv * 4 + (lc >> 3);
        epA[ib * PAD_K + mcol]       = f2bf(g0);
        epA[(ib + 2) * PAD_K + mcol] = f2bf(g1);
    }

    // ---- epilogue B-frags from sd/se (pre-barrier; dd = wv*16+lc)
    const int dd = wv * 16 + lc;
    bf16x8 bd, be;
    {
        unsigned dv[8], ev[8];
#pragma unroll
        for (int j = 0; j < 8; ++j) {
            dv[j] = *reinterpret_cast<const unsigned short*>(&sd[(ko * 8 + j) * PAD_K + dd]);
            ev[j] = *reinterpret_cast<const unsigned short*>(&se[(ko * 8 + j) * PAD_K + dd]);
        }
        union { unsigned u[4]; bf16x8 v; } td, te;
#pragma unroll
        for (int j = 0; j < 4; ++j) {
            td.u[j] = __builtin_amdgcn_perm(dv[2 * j + 1], dv[2 * j], 0x05040100);
            te.u[j] = __builtin_amdgcn_perm(ev[2 * j + 1], ev[2 * j], 0x05040100);
        }
        bd = td.v; be = te.v;
    }
    __syncthreads();   // B2

    // ---- cooperative epilogue MFMA
    bf16x8 apm = *reinterpret_cast<const bf16x8*>(&epA[lc * PAD_K + ko * 8]);
    bf16x8 apl = *reinterpret_cast<const bf16x8*>(&epA[lc * PAD_K + 32 + ko * 8]);
    f32x4 zacc = (f32x4){0.f, 0.f, 0.f, 0.f};
    zacc = __builtin_amdgcn_mfma_f32_16x16x32_bf16(apm, bd, zacc, 0, 0, 0);
    zacc = __builtin_amdgcn_mfma_f32_16x16x32_bf16(apl, be, zacc, 0, 0, 0);

    // ---- z repack in LDS (sd is dead after B2) then coalesced store
    short* zs = sd;
#pragma unroll
    for (int reg = 0; reg < 4; ++reg) {
        int i = ko * 4 + reg;
        zs[i * 64 + dd] = f2bf(zacc[reg] * sinv[i]);
    }
    __syncthreads();   // B3
    {
        int row = tid >> 4;            // 0..15
        int ch  = (tid & 15) * 4;      // 4 shorts = 8B
        *reinterpret_cast<uint2*>(
            &z[((size_t)b * T_SEQ + nbase + row) * (NHEADS * DHEAD) + hd + ch]) =
            *reinterpret_cast<const uint2*>(&zs[row * 64 + ch]);
    }
}

// ---------------------------------------------------------------------------
extern "C" void kernel_launch(void* const* d_in, const int* in_sizes, int n_in,
                              void* d_out, int out_size, void* d_ws, size_t ws_size,
                              hipStream_t stream) {
    const float* x        = (const float*)d_in[0];
    const float* W_abcde  = (const float*)d_in[1];
    const float* b_abcde  = (const float*)d_in[2];
    const float* W_O      = (const float*)d_in[3];
    const float* b_O      = (const float*)d_in[4];
    float* out = (float*)d_out;

    char* ws = (char*)d_ws;
    short* abcde = (short*)ws;                                  // 4096x3840 bf16 (31.5 MB)
    short* xb    = (short*)(ws + (size_t)31457280);             // 4096x768 bf16, reused as zb
    short* Wt    = (short*)(ws + (size_t)31457280 + 6291456);   // 3840x768 bf16
    short* WOt   = (short*)(ws + (size_t)31457280 + 6291456 + 5898240); // 768x768 bf16
    short* zb    = xb;

    const int M = 2 * T_SEQ;  // 4096

    prep_kernel<<<dim3(4992), dim3(256), 0, stream>>>(
        x, W_abcde, W_O, xb, Wt, WOt);

    gemm1_kernel<<<dim3(1920), dim3(256), 0, stream>>>(
        xb, Wt, b_abcde, abcde, M, NABCDE, DMODEL);

    attn_kernel<<<dim3(2 * NHEADS * NWIN), dim3(256), 0, stream>>>(abcde, zb);

    gemm_bf16_64<<<dim3(DMODEL / 64, M / 64), dim3(256), 0, stream>>>(
        zb, WOt, b_O, out, M, DMODEL, DMODEL);
}